// Round 20
// baseline (420.448 us; speedup 1.0000x reference)
//
#include <hip/hip_runtime.h>
#include <hip/hip_bf16.h>

typedef __hip_bfloat16 bf16;
typedef __attribute__((ext_vector_type(8))) short short8v;
typedef __attribute__((ext_vector_type(4))) float f32x4;

static inline int cdiv(long long a, int b){ return (int)((a + b - 1) / b); }

__device__ __forceinline__ float uaf(unsigned u){ return __uint_as_float(u); }
__device__ __forceinline__ float ldf(const bf16* p){ return __bfloat162float(*p); }
__device__ __forceinline__ void stf(bf16* p, float v){ *p = __float2bfloat16(v); }

__device__ __forceinline__ void load4v(const float* p, float& a, float& b, float& c, float& d){
    float4 v = *reinterpret_cast<const float4*>(p); a = v.x; b = v.y; c = v.z; d = v.w;
}
__device__ __forceinline__ unsigned short bfbits(float v){
    bf16 h = __float2bfloat16(v); unsigned short s; __builtin_memcpy(&s, &h, 2); return s;
}

// ====================== HALO ZEROING ======================
__global__ void halo2d_k(bf16* buf, long long bstride, int nsub, long long sstride,
                         int Hp, int Wp, int Cv)
{
    int z = blockIdx.z;
    bf16* b = buf + (long long)(z / nsub) * bstride + (long long)(z % nsub) * sstride;
    uint4 zz = make_uint4(0, 0, 0, 0);
    int rowV = Wp * Cv;
    int totalV = 2 * rowV + (Hp - 2) * 2 * Cv;
    for (int i = blockIdx.x * 256 + threadIdx.x; i < totalV; i += gridDim.x * 256) {
        long long off;
        if (i < rowV) off = i;
        else if (i < 2 * rowV) off = (long long)(Hp - 1) * rowV + (i - rowV);
        else {
            int k = i - 2 * rowV;
            int h = 1 + k / (2 * Cv);
            int r = k % (2 * Cv);
            int wc = (r < Cv) ? 0 : (Wp - 1);
            off = (long long)h * rowV + (long long)wc * Cv + (r < Cv ? r : r - Cv);
        }
        reinterpret_cast<uint4*>(b)[off] = zz;
    }
}

__global__ void zero_planes_k(bf16* buf, long long bstride, long long planeV, int lastPlane)
{
    int b = blockIdx.z, p = blockIdx.y;
    uint4 zz = make_uint4(0, 0, 0, 0);
    bf16* base = buf + (long long)b * bstride;
    long long pl = p ? (long long)lastPlane * planeV : 0;
    for (long long i = blockIdx.x * 256 + threadIdx.x; i < planeV; i += (long long)gridDim.x * 256)
        reinterpret_cast<uint4*>(base)[pl + i] = zz;
}

// ====================== ENCODER (NHWC bf16 chain) ======================
#define E12_BS 2396288LL   // bytes per img, 194*386*16*2
#define E3_BS  1216768LL   // 98*194*32*2

__global__ __launch_bounds__(256) void conv_e1(
    const float* __restrict__ in0, const float* __restrict__ in1,
    const float* __restrict__ w, const float* __restrict__ sc, const float* __restrict__ bi,
    bf16* __restrict__ out)
{
    const int H = 384, W = 768, NW = 96;
    int img = blockIdx.z;
    const float* in = (img >= 4) ? in1 + (long long)(img - 4) * 3 * 294912
                                 : in0 + (long long)img * 3 * 294912;

    __shared__ float wl[432];
    __shared__ float sl[16], bl[16];
    for (int j = threadIdx.x; j < 432; j += 256) {
        int k = j / 16, o = j % 16;
        wl[j] = w[o * 27 + k];
    }
    if (threadIdx.x < 16) { sl[threadIdx.x] = sc[threadIdx.x]; bl[threadIdx.x] = bi[threadIdx.x]; }
    __syncthreads();

    int unit = blockIdx.x * 256 + threadIdx.x;
    int h = unit / NW, wseg = unit % NW, w0 = wseg << 2;
    const long long HW = (long long)H * W;

    float acc[16][4];
#pragma unroll
    for (int o = 0; o < 16; ++o){ acc[o][0]=0.f; acc[o][1]=0.f; acc[o][2]=0.f; acc[o][3]=0.f; }

    for (int ic = 0; ic < 3; ++ic) {
        const float* ip = in + (long long)ic * HW;
#pragma unroll
        for (int kh = 0; kh < 3; ++kh) {
            int ih = 2 * h + kh - 1;
            if (ih < 0 || ih >= H) continue;
            const float* row = ip + (long long)ih * W;
            float x0,x1,x2,x3,x4,x5,x6,x7;
            load4v(row + 2 * w0,     x0, x1, x2, x3);
            load4v(row + 2 * w0 + 4, x4, x5, x6, x7);
            float xm = (w0 > 0) ? row[2 * w0 - 1] : 0.f;
            const float* wk = wl + (ic * 9 + kh * 3) * 16;
#pragma unroll
            for (int o = 0; o < 16; ++o) {
                float wa = wk[o], wb = wk[16 + o], wc = wk[32 + o];
                acc[o][0] = fmaf(xm, wa, fmaf(x0, wb, fmaf(x1, wc, acc[o][0])));
                acc[o][1] = fmaf(x1, wa, fmaf(x2, wb, fmaf(x3, wc, acc[o][1])));
                acc[o][2] = fmaf(x3, wa, fmaf(x4, wb, fmaf(x5, wc, acc[o][2])));
                acc[o][3] = fmaf(x5, wa, fmaf(x6, wb, fmaf(x7, wc, acc[o][3])));
            }
        }
    }
    char* ob = (char*)out + (long long)img * E12_BS;
#pragma unroll
    for (int i = 0; i < 4; ++i) {
        float v[16];
#pragma unroll
        for (int o = 0; o < 16; ++o) v[o] = fmaxf(acc[o][i] * sl[o] + bl[o], 0.f);
        uint4 u0, u1;
        u0.x = (unsigned)bfbits(v[0])  | ((unsigned)bfbits(v[1])  << 16);
        u0.y = (unsigned)bfbits(v[2])  | ((unsigned)bfbits(v[3])  << 16);
        u0.z = (unsigned)bfbits(v[4])  | ((unsigned)bfbits(v[5])  << 16);
        u0.w = (unsigned)bfbits(v[6])  | ((unsigned)bfbits(v[7])  << 16);
        u1.x = (unsigned)bfbits(v[8])  | ((unsigned)bfbits(v[9])  << 16);
        u1.y = (unsigned)bfbits(v[10]) | ((unsigned)bfbits(v[11]) << 16);
        u1.z = (unsigned)bfbits(v[12]) | ((unsigned)bfbits(v[13]) << 16);
        u1.w = (unsigned)bfbits(v[14]) | ((unsigned)bfbits(v[15]) << 16);
        char* p = ob + ((long long)(h + 1) * 386 + (w0 + i + 1)) * 32;
        *reinterpret_cast<uint4*>(p)      = u0;
        *reinterpret_cast<uint4*>(p + 16) = u1;
    }
}

__global__ __launch_bounds__(256) void conv_e2_mfma(
    const bf16* __restrict__ in, const float* __restrict__ w,
    const float* __restrict__ sc, const float* __restrict__ bi,
    bf16* __restrict__ out)
{
    __shared__ short alds[16 * 160];
    __shared__ int offl[20];
    int tid = threadIdx.x;
    for (int j = tid; j < 16 * 160; j += 256) {
        int oc = j / 160, kk = j % 160;
        short v = 0;
        if (kk < 144) { int tap = kk / 16, ic = kk % 16; v = (short)bfbits(w[oc * 144 + ic * 9 + tap]); }
        alds[j] = v;
    }
    if (tid < 20) {
        int c = tid / 4, g = tid % 4;
        int tap = 2 * c + (g >> 1); if (tap > 8) tap = 8;
        offl[tid] = ((tap / 3) * 386 + (tap % 3)) * 32 + (g & 1) * 16;
    }
    __syncthreads();

    int wid = tid >> 6, lane = tid & 63;
    int wt = blockIdx.x * 4 + wid;
    int h = wt / 6, w0 = (wt % 6) * 64;
    int img = blockIdx.z;
    int g = lane >> 4, px = lane & 15;

    const char* bp = (const char*)in + (long long)img * E12_BS
                   + ((long long)h * 386 + (w0 + px)) * 32;
    int offr[5];
#pragma unroll
    for (int c = 0; c < 5; ++c) offr[c] = offl[c * 4 + g];
    short8v af[5];
#pragma unroll
    for (int c = 0; c < 5; ++c)
        af[c] = *reinterpret_cast<const short8v*>(&alds[px * 160 + 32 * c + 8 * g]);

    f32x4 acc[4];
#pragma unroll
    for (int pg = 0; pg < 4; ++pg) {
        f32x4 a = {0.f, 0.f, 0.f, 0.f};
        const char* bpp = bp + pg * 512;
#pragma unroll
        for (int c = 0; c < 5; ++c) {
            short8v bf = *reinterpret_cast<const short8v*>(bpp + offr[c]);
            a = __builtin_amdgcn_mfma_f32_16x16x32_bf16(af[c], bf, a, 0, 0, 0);
        }
        acc[pg] = a;
    }
    char* ob = (char*)out + (long long)img * E12_BS;
#pragma unroll
    for (int pg = 0; pg < 4; ++pg) {
        float v[4];
#pragma unroll
        for (int r = 0; r < 4; ++r) {
            int oc = g * 4 + r;
            v[r] = fmaxf(acc[pg][r] * sc[oc] + bi[oc], 0.f);
        }
        uint2 u;
        u.x = (unsigned)bfbits(v[0]) | ((unsigned)bfbits(v[1]) << 16);
        u.y = (unsigned)bfbits(v[2]) | ((unsigned)bfbits(v[3]) << 16);
        *reinterpret_cast<uint2*>(ob + ((long long)(h + 1) * 386 + (w0 + pg * 16 + px + 1)) * 32 + g * 8) = u;
    }
}

__global__ __launch_bounds__(256) void conv_e3_mfma(
    const bf16* __restrict__ in, const float* __restrict__ w,
    const float* __restrict__ sc, const float* __restrict__ bi,
    bf16* __restrict__ out)
{
    __shared__ short alds[16 * 160];
    __shared__ int offl[20];
    int tid = threadIdx.x;
    int och = blockIdx.y;
    for (int j = tid; j < 16 * 160; j += 256) {
        int oc = j / 160, kk = j % 160;
        short v = 0;
        if (kk < 144) { int tap = kk / 16, ic = kk % 16; v = (short)bfbits(w[(och * 16 + oc) * 144 + ic * 9 + tap]); }
        alds[j] = v;
    }
    if (tid < 20) {
        int c = tid / 4, g = tid % 4;
        int tap = 2 * c + (g >> 1); if (tap > 8) tap = 8;
        offl[tid] = ((tap / 3) * 386 + (tap % 3)) * 32 + (g & 1) * 16;
    }
    __syncthreads();

    int wid = tid >> 6, lane = tid & 63;
    int wt = blockIdx.x * 4 + wid;
    int h = wt / 3, w0 = (wt % 3) * 64;
    int img = blockIdx.z;
    int g = lane >> 4, px = lane & 15;

    const char* bp = (const char*)in + (long long)img * E12_BS
                   + ((long long)(2 * h) * 386 + 2 * (w0 + px)) * 32;
    int offr[5];
#pragma unroll
    for (int c = 0; c < 5; ++c) offr[c] = offl[c * 4 + g];
    short8v af[5];
#pragma unroll
    for (int c = 0; c < 5; ++c)
        af[c] = *reinterpret_cast<const short8v*>(&alds[px * 160 + 32 * c + 8 * g]);

    f32x4 acc[4];
#pragma unroll
    for (int pg = 0; pg < 4; ++pg) {
        f32x4 a = {0.f, 0.f, 0.f, 0.f};
        const char* bpp = bp + pg * 1024;
#pragma unroll
        for (int c = 0; c < 5; ++c) {
            short8v bf = *reinterpret_cast<const short8v*>(bpp + offr[c]);
            a = __builtin_amdgcn_mfma_f32_16x16x32_bf16(af[c], bf, a, 0, 0, 0);
        }
        acc[pg] = a;
    }
    char* ob = (char*)out + (long long)img * E3_BS;
#pragma unroll
    for (int pg = 0; pg < 4; ++pg) {
        float v[4];
#pragma unroll
        for (int r = 0; r < 4; ++r) {
            int oc = och * 16 + g * 4 + r;
            v[r] = fmaxf(acc[pg][r] * sc[oc] + bi[oc], 0.f);
        }
        uint2 u;
        u.x = (unsigned)bfbits(v[0]) | ((unsigned)bfbits(v[1]) << 16);
        u.y = (unsigned)bfbits(v[2]) | ((unsigned)bfbits(v[3]) << 16);
        *reinterpret_cast<uint2*>(ob + ((long long)(h + 1) * 194 + (w0 + pg * 16 + px + 1)) * 64
                                  + och * 32 + g * 8) = u;
    }
}

__global__ __launch_bounds__(256) void conv_e4_mfma(
    const bf16* __restrict__ in, const float* __restrict__ w,
    const float* __restrict__ sc, const float* __restrict__ bi,
    float* __restrict__ fl, float* __restrict__ fr)
{
    __shared__ short alds[16 * 288];
    __shared__ int offl[36];
    int tid = threadIdx.x;
    int och = blockIdx.y;
    for (int j = tid; j < 16 * 288; j += 256) {
        int oc = j / 288, kk = j % 288;
        int tap = kk / 32, ic = kk % 32;
        alds[j] = (short)bfbits(w[(och * 16 + oc) * 288 + ic * 9 + tap]);
    }
    if (tid < 36) {
        int c = tid / 4, g = tid % 4;
        offl[tid] = ((c / 3) * 194 + (c % 3)) * 64 + g * 16;
    }
    __syncthreads();

    int wid = tid >> 6, lane = tid & 63;
    int wt = blockIdx.x * 4 + wid;
    int h = wt / 3, w0 = (wt % 3) * 64;
    int img = blockIdx.z;
    int g = lane >> 4, px = lane & 15;

    const char* bp = (const char*)in + (long long)img * E3_BS
                   + ((long long)h * 194 + (w0 + px)) * 64;
    int offr[9];
#pragma unroll
    for (int c = 0; c < 9; ++c) offr[c] = offl[c * 4 + g];
    short8v af[9];
#pragma unroll
    for (int c = 0; c < 9; ++c)
        af[c] = *reinterpret_cast<const short8v*>(&alds[px * 288 + 32 * c + 8 * g]);

    f32x4 acc[4];
#pragma unroll
    for (int pg = 0; pg < 4; ++pg) {
        f32x4 a = {0.f, 0.f, 0.f, 0.f};
        const char* bpp = bp + pg * 1024;
#pragma unroll
        for (int c = 0; c < 9; ++c) {
            short8v bf = *reinterpret_cast<const short8v*>(bpp + offr[c]);
            a = __builtin_amdgcn_mfma_f32_16x16x32_bf16(af[c], bf, a, 0, 0, 0);
        }
        acc[pg] = a;
    }
    float* dst = (img < 4) ? fl + (long long)img * 32 * 18432
                           : fr + (long long)(img - 4) * 32 * 18432;
#pragma unroll
    for (int pg = 0; pg < 4; ++pg) {
#pragma unroll
        for (int r = 0; r < 4; ++r) {
            int oc = och * 16 + g * 4 + r;
            float v = fmaxf(acc[pg][r] * sc[oc] + bi[oc], 0.f);
            dst[(long long)oc * 18432 + (long long)h * 192 + w0 + pg * 16 + px] = v;
        }
    }
}

// ====================== AGGREGATION (2-batch super-batch, full-D) ======================
#define PB1E 7604800LL     // C1pad elems per buffer (50*98*194*8)
#define PB2E 15209600LL    // C2pad elems per buffer (50*98*194*16)

__global__ __launch_bounds__(256) void conv1_nhwc(
    const float* __restrict__ in, const float* __restrict__ w,
    const float* __restrict__ sc, const float* __restrict__ bi,
    bf16* __restrict__ out)
{
    const int H = 96, W = 192, D = 48, NW = 48;
    int zb = blockIdx.z;
    const float* inz = in + (long long)zb * 884736;
    bf16* outz = out + (long long)zb * PB1E;
    int d = blockIdx.y;
    __shared__ float wl[216];
    __shared__ float sl[8], bl[8];
    for (int j = threadIdx.x; j < 216; j += 256) wl[j] = w[j];
    if (threadIdx.x < 8) { sl[threadIdx.x] = sc[threadIdx.x]; bl[threadIdx.x] = bi[threadIdx.x]; }
    __syncthreads();

    int unit = blockIdx.x * 256 + threadIdx.x;
    int h = unit / NW, wseg = unit % NW, w0 = wseg << 2;
    if (h >= H) return;

    float acc[8][4];
#pragma unroll
    for (int o = 0; o < 8; ++o){ acc[o][0]=0.f; acc[o][1]=0.f; acc[o][2]=0.f; acc[o][3]=0.f; }

#pragma unroll
    for (int kd = 0; kd < 3; ++kd) {
        int id = d + kd - 1;
        if (id < 0 || id >= D) continue;
        const float* plane = inz + (long long)id * H * W;
#pragma unroll
        for (int kh = 0; kh < 3; ++kh) {
            int ih = h + kh - 1;
            if (ih < 0 || ih >= H) continue;
            const float* row = plane + (long long)ih * W;
            float x0,x1,x2,x3;
            load4v(row + w0, x0, x1, x2, x3);
            float xl = (wseg > 0)      ? row[w0 - 1] : 0.f;
            float xr = (wseg < NW - 1) ? row[w0 + 4] : 0.f;
            int kb = kd * 9 + kh * 3;
#pragma unroll
            for (int o = 0; o < 8; ++o) {
                float wa = wl[o*27 + kb], wb = wl[o*27 + kb + 1], wc = wl[o*27 + kb + 2];
                acc[o][0] = fmaf(xl, wa, fmaf(x0, wb, fmaf(x1, wc, acc[o][0])));
                acc[o][1] = fmaf(x0, wa, fmaf(x1, wb, fmaf(x2, wc, acc[o][1])));
                acc[o][2] = fmaf(x1, wa, fmaf(x2, wb, fmaf(x3, wc, acc[o][2])));
                acc[o][3] = fmaf(x2, wa, fmaf(x3, wb, fmaf(xr, wc, acc[o][3])));
            }
        }
    }
#pragma unroll
    for (int i = 0; i < 4; ++i) {
        uint4 u;
        float v[8];
#pragma unroll
        for (int o = 0; o < 8; ++o) v[o] = fmaxf(acc[o][i] * sl[o] + bl[o], 0.f);
        u.x = (unsigned)bfbits(v[0]) | ((unsigned)bfbits(v[1]) << 16);
        u.y = (unsigned)bfbits(v[2]) | ((unsigned)bfbits(v[3]) << 16);
        u.z = (unsigned)bfbits(v[4]) | ((unsigned)bfbits(v[5]) << 16);
        u.w = (unsigned)bfbits(v[6]) | ((unsigned)bfbits(v[7]) << 16);
        long long idx = (((long long)(d + 1) * 98 + (h + 1)) * 194 + (w0 + 1 + i)) * 8;
        *reinterpret_cast<uint4*>(&outz[idx]) = u;
    }
}

__global__ __launch_bounds__(256) void conv2_mfma(
    const bf16* __restrict__ in, const float* __restrict__ w,
    const float* __restrict__ sc, const float* __restrict__ bi,
    bf16* __restrict__ out)
{
    __shared__ short alds[16 * 224];
    __shared__ uint4 sB[6 * 3 * 66];
    __shared__ int offl[28];
    int tid = threadIdx.x;
    int zb = blockIdx.z;
    const bf16* inz = in + (long long)zb * PB1E;
    for (int j = tid; j < 16 * 224; j += 256) {
        int oc = j / 224, kk = j % 224;
        short v = 0;
        if (kk < 216) { int t = kk / 8, ic = kk % 8; v = (short)bfbits(w[(oc * 8 + ic) * 27 + t]); }
        alds[j] = v;
    }
    if (tid < 28) {
        int t = (tid < 27) ? tid : 26;
        int kd = t / 9, kh = (t / 3) % 3, kw = t % 3;
        offl[tid] = (kd * 3 + kh) * 66 + kw;
    }

    int hw = blockIdx.x;
    int h = hw / 3, w0 = (hw % 3) * 64;
    int dq = blockIdx.y * 4;
    for (int j = tid; j < 1188; j += 256) {
        int p = j / 198, rem = j % 198;
        int r = rem / 66, c = rem % 66;
        sB[j] = *reinterpret_cast<const uint4*>(
            inz + (((long long)(dq + p) * 98 + (h + r)) * 194 + (w0 + c)) * 8);
    }
    __syncthreads();

    int wid = tid >> 6, lane = tid & 63;
    int g = lane >> 4, px = lane & 15;
    int d = dq + wid;

    const uint4* sBw = sB + wid * 198;
    int offr[7];
#pragma unroll
    for (int c = 0; c < 7; ++c) offr[c] = offl[4 * c + g];
    short8v af[7];
#pragma unroll
    for (int c = 0; c < 7; ++c)
        af[c] = *reinterpret_cast<const short8v*>(&alds[px * 224 + 32 * c + 8 * g]);

    f32x4 acc[4];
#pragma unroll
    for (int pg = 0; pg < 4; ++pg) {
        f32x4 a = {0.f, 0.f, 0.f, 0.f};
        int col = pg * 16 + px;
#pragma unroll
        for (int c = 0; c < 7; ++c) {
            short8v bf = *reinterpret_cast<const short8v*>(&sBw[offr[c] + col]);
            a = __builtin_amdgcn_mfma_f32_16x16x32_bf16(af[c], bf, a, 0, 0, 0);
        }
        acc[pg] = a;
    }

    char* ob = (char*)(out + (long long)zb * PB2E);
#pragma unroll
    for (int pg = 0; pg < 4; ++pg) {
        float v[4];
#pragma unroll
        for (int r = 0; r < 4; ++r) {
            int oc = g * 4 + r;
            v[r] = fmaxf(acc[pg][r] * sc[oc] + bi[oc], 0.f);
        }
        long long pxi = ((long long)(d + 1) * 98 + h + 1) * 194 + (w0 + pg * 16 + px + 1);
        uint2 u;
        u.x = (unsigned)bfbits(v[0]) | ((unsigned)bfbits(v[1]) << 16);
        u.y = (unsigned)bfbits(v[2]) | ((unsigned)bfbits(v[3]) << 16);
        *reinterpret_cast<uint2*>(ob + pxi * 32 + g * 8) = u;
    }
}

// ---- conv3 (16->1), DBLK=4 x 2 W-out/thread (round-20: cut d-overlap refetch). grid (36,12,2) ----
__global__ __launch_bounds__(256) void conv3_nhwc(
    const bf16* __restrict__ in, const float* __restrict__ w,
    float* __restrict__ out)
{
    const int H = 96, W = 192, D = 48, NW = 96;
    __shared__ float wl[27][16];
    for (int j = threadIdx.x; j < 432; j += 256) wl[j / 16][j % 16] = w[(j % 16) * 27 + j / 16];
    __syncthreads();

    int zb = blockIdx.z;
    const bf16* inz = in + (long long)zb * PB2E;
    float* outz = out + (long long)zb * 884736;
    int dl0 = blockIdx.y * 4;                    // 4 consecutive d-outputs
    int unit = blockIdx.x * 256 + threadIdx.x;
    int h = unit / NW, wseg = unit % NW, w0 = wseg * 2;

    float acc[4][2];
#pragma unroll
    for (int o = 0; o < 4; ++o){ acc[o][0]=0.f; acc[o][1]=0.f; }

    // slices s=0..5 -> global plane gid = dl0-1+s; output o uses it as kd = s-o.
#pragma unroll
    for (int s = 0; s < 6; ++s) {
        int gid = dl0 - 1 + s;
        if (gid < 0 || gid >= D) continue;       // block-uniform
        int il = gid + 1;                        // padded plane index
        const char* plane = (const char*)inz + (long long)il * 98 * 194 * 32;
#pragma unroll
        for (int kh = 0; kh < 3; ++kh) {
            const char* base = plane + ((long long)(h + kh) * 194 + w0) * 32;
#pragma unroll
            for (int hf = 0; hf < 2; ++hf) {
#pragma unroll
                for (int p = 0; p < 4; ++p) {
                    uint4 q = *reinterpret_cast<const uint4*>(base + p * 32 + hf * 16);
                    float x[8];
                    x[0]=uaf(q.x<<16); x[1]=uaf(q.x&0xffff0000u);
                    x[2]=uaf(q.y<<16); x[3]=uaf(q.y&0xffff0000u);
                    x[4]=uaf(q.z<<16); x[5]=uaf(q.z&0xffff0000u);
                    x[6]=uaf(q.w<<16); x[7]=uaf(q.w&0xffff0000u);
#pragma unroll
                    for (int o = 0; o < 4; ++o) {
                        int kd = s - o;
                        if (kd < 0 || kd > 2) continue;          // compile-time
#pragma unroll
                        for (int kw = 0; kw < 3; ++kw) {
                            int i = p - kw;
                            if (i < 0 || i > 1) continue;        // compile-time
                            const int t = kd * 9 + kh * 3 + kw;
                            float sum = 0.f;
#pragma unroll
                            for (int c = 0; c < 8; ++c) sum = fmaf(x[c], wl[t][hf * 8 + c], sum);
                            acc[o][i] += sum;
                        }
                    }
                }
            }
        }
    }
#pragma unroll
    for (int o = 0; o < 4; ++o) {
        float* op = outz + ((long long)(dl0 + o) * H + h) * W + w0;
        *reinterpret_cast<float2*>(op) = make_float2(acc[o][0], acc[o][1]);
    }
}

// ====================== REST ======================
__global__ __launch_bounds__(256) void corr2_k(
    const float* __restrict__ fl, const float* __restrict__ fr,
    float* __restrict__ cost)
{
    const int C = 32, D = 48, H = 96, W = 192;
    __shared__ float sfl[64 * 33];
    __shared__ float sfr[111 * 33];

    int w0 = blockIdx.x * 64, h = blockIdx.y, b = blockIdx.z;
    int tid = threadIdx.x;

    for (int j = tid; j < 64 * C; j += 256) {
        int w = j % 64, c = j / 64;
        sfl[w * 33 + c] = fl[(((long long)b * C + c) * H + h) * W + w0 + w];
    }
    for (int j = tid; j < 111 * C; j += 256) {
        int wp = j % 111, c = j / 111;
        int gw = w0 - 47 + wp;
        sfr[wp * 33 + c] = (gw >= 0) ? fr[(((long long)b * C + c) * H + h) * W + gw] : 0.f;
    }
    __syncthreads();

    int w = tid & 63, dg = tid >> 6;
    float flr[32];
#pragma unroll
    for (int c = 0; c < 32; ++c) flr[c] = sfl[w * 33 + c];

    for (int dd = 0; dd < 12; ++dd) {
        int d = dg * 12 + dd;
        int wi = w - d + 47;
        float a = 0.f;
#pragma unroll
        for (int c = 0; c < 32; ++c) a = fmaf(flr[c], sfr[wi * 33 + c], a);
        cost[(((long long)b * D + d) * H + h) * W + w0 + w] = a * (1.0f / 32.0f);
    }
}

__global__ void softdisp_k(const float* __restrict__ c3, float* __restrict__ dl,
                           int B, int H, int W)
{
    const int D = 48;
    long long idx = (long long)blockIdx.x * blockDim.x + threadIdx.x;
    long long total = (long long)B * H * W;
    if (idx >= total) return;
    int b = (int)(idx / ((long long)H * W));
    long long rem = idx % ((long long)H * W);
    const float* p = c3 + ((long long)b * D) * H * W + rem;
    long long st = (long long)H * W;

    float v[48];
    float mn = 1e30f;
#pragma unroll
    for (int d = 0; d < D; ++d) { v[d] = p[d * st]; mn = fminf(mn, v[d]); }
    float se = 0.f, sd = 0.f;
#pragma unroll
    for (int d = 0; d < D; ++d) {
        float e = expf(mn - v[d]);
        se += e;
        sd += e * (float)d;
    }
    dl[idx] = sd / se;
}

// ---- fused refinement with inline bilinear upsample from DL ----
__global__ __launch_bounds__(256) void refine_fused(
    const float* __restrict__ dlow, const float* __restrict__ w1,
    const float* __restrict__ s1, const float* __restrict__ b1,
    const float* __restrict__ w2, float* __restrict__ out)
{
    const int H = 384, W = 768, Hl = 96, Wl = 192;
    __shared__ float sdu[20][21];
    __shared__ float smid[18][18][20];
    __shared__ float w1l[144], s1l[16], b1l[16], w2l[144];
    int tid = threadIdx.x;
    if (tid < 144) {
        w1l[tid] = w1[tid];
        int ic = tid / 9, tap = tid % 9;
        w2l[tap * 16 + ic] = w2[tid];
    } else if (tid < 160) {
        s1l[tid - 144] = s1[tid - 144]; b1l[tid - 144] = b1[tid - 144];
    }

    int b = blockIdx.z, h0 = blockIdx.y * 16, w0 = blockIdx.x * 16;
    const float* dlb = dlow + (long long)b * Hl * Wl;
    for (int j = tid; j < 400; j += 256) {
        int i = j / 20, k = j % 20;
        int y = h0 - 2 + i, x = w0 - 2 + k;
        float v = 0.f;
        if (y >= 0 && y < H && x >= 0 && x < W) {
            float sy = (y + 0.5f) * 0.25f - 0.5f;
            float sx = (x + 0.5f) * 0.25f - 0.5f;
            sy = fminf(fmaxf(sy, 0.f), (float)(Hl - 1));
            sx = fminf(fmaxf(sx, 0.f), (float)(Wl - 1));
            int y0 = (int)sy, x0 = (int)sx;
            int y1 = min(y0 + 1, Hl - 1), x1 = min(x0 + 1, Wl - 1);
            float fy = sy - y0, fx = sx - x0;
            v = 4.0f * ((1.f - fy) * ((1.f - fx) * dlb[y0 * Wl + x0] + fx * dlb[y0 * Wl + x1])
                      +        fy  * ((1.f - fx) * dlb[y1 * Wl + x0] + fx * dlb[y1 * Wl + x1]));
        }
        sdu[i][k] = v;
    }
    __syncthreads();

    for (int idx = tid; idx < 324; idx += 256) {
        int i = idx / 18, j = idx % 18;
        int gy = h0 - 1 + i, gx = w0 - 1 + j;
        bool inimg = (gy >= 0 && gy < H && gx >= 0 && gx < W);
        float t[9];
#pragma unroll
        for (int kh = 0; kh < 3; ++kh)
#pragma unroll
            for (int kw = 0; kw < 3; ++kw) t[kh * 3 + kw] = sdu[i + kh][j + kw];
        float m[16];
#pragma unroll
        for (int oc = 0; oc < 16; ++oc) {
            float s = 0.f;
#pragma unroll
            for (int k = 0; k < 9; ++k) s = fmaf(t[k], w1l[oc * 9 + k], s);
            m[oc] = inimg ? fmaxf(s * s1l[oc] + b1l[oc], 0.f) : 0.f;
        }
#pragma unroll
        for (int q = 0; q < 4; ++q)
            *reinterpret_cast<float4*>(&smid[i][j][q * 4]) =
                make_float4(m[q*4], m[q*4+1], m[q*4+2], m[q*4+3]);
    }
    __syncthreads();

    int i = tid >> 4, j = tid & 15;
    float s = 0.f;
#pragma unroll
    for (int kh = 0; kh < 3; ++kh)
#pragma unroll
        for (int kw = 0; kw < 3; ++kw) {
            const float* mp = &smid[i + kh][j + kw][0];
            const float* wp = &w2l[(kh * 3 + kw) * 16];
#pragma unroll
            for (int q = 0; q < 4; ++q) {
                float4 x = *reinterpret_cast<const float4*>(mp + q * 4);
                s = fmaf(x.x, wp[q*4+0], s);
                s = fmaf(x.y, wp[q*4+1], s);
                s = fmaf(x.z, wp[q*4+2], s);
                s = fmaf(x.w, wp[q*4+3], s);
            }
        }
    out[(long long)b * H * W + (long long)(h0 + i) * W + w0 + j] = fmaxf(s, 0.f);
}

extern "C" void kernel_launch(void* const* d_in, const int* in_sizes, int n_in,
                              void* d_out, int out_size, void* d_ws, size_t ws_size,
                              hipStream_t stream)
{
    const float* img_l = (const float*)d_in[0];
    const float* img_r = (const float*)d_in[1];
    const float* e_w1 = (const float*)d_in[2];
    const float* e_w2 = (const float*)d_in[3];
    const float* e_w3 = (const float*)d_in[4];
    const float* e_w4 = (const float*)d_in[5];
    const float* e_s1 = (const float*)d_in[6];
    const float* e_s2 = (const float*)d_in[7];
    const float* e_s3 = (const float*)d_in[8];
    const float* e_s4 = (const float*)d_in[9];
    const float* e_b1 = (const float*)d_in[10];
    const float* e_b2 = (const float*)d_in[11];
    const float* e_b3 = (const float*)d_in[12];
    const float* e_b4 = (const float*)d_in[13];
    const float* a_w1 = (const float*)d_in[14];
    const float* a_s1 = (const float*)d_in[15];
    const float* a_b1 = (const float*)d_in[16];
    const float* a_w2 = (const float*)d_in[17];
    const float* a_s2 = (const float*)d_in[18];
    const float* a_b2 = (const float*)d_in[19];
    const float* a_w3 = (const float*)d_in[20];
    const float* r_w1 = (const float*)d_in[21];
    const float* r_s1 = (const float*)d_in[22];
    const float* r_b1 = (const float*)d_in[23];
    const float* r_w2 = (const float*)d_in[24];

    const int B = 4, H = 384, W = 768, H4 = 96, W4 = 192, D = 48;
    const long long HW4 = (long long)H4 * W4;
    const long long DHW = (long long)D * HW4;
    const long long E12E = E12_BS / 2;
    const long long P1E = 98LL * 194 * 8;
    const long long P2E = 98LL * 194 * 16;

    float* out_disp = (float*)d_out;
    float* FL       = out_disp + 1179648;

    // ---- workspace layout (peak ~105.7 MB) ----
    char* ws = (char*)d_ws;
    bf16*  E1pad = (bf16*)(ws + 0);
    bf16*  E2pad = (bf16*)(ws + 19170304);
    bf16*  E3pad = (bf16*)(ws + 38340608);
    float* FR    = (float*)(ws + 48074752);
    float* COST  = (float*)(ws + 0);
    bf16*  C1pad = (bf16*) (ws + 14155776);
    bf16*  C2pad = (bf16*) (ws + 44574976);
    float* C3    = COST;
    float* DL    = (float*)(ws + 105413376);

    dim3 blk(256);

    halo2d_k<<<dim3(10, 1, 16), blk, 0, stream>>>(E1pad, E12E, 1, 0, 194, 386, 2);
    halo2d_k<<<dim3(10, 1, 8),  blk, 0, stream>>>(E3pad, E3_BS / 2, 1, 0, 98, 194, 4);

    conv_e1<<<dim3(72, 1, 8), blk, 0, stream>>>(img_l, img_r, e_w1, e_s1, e_b1, E1pad);
    conv_e2_mfma<<<dim3(288, 1, 8), blk, 0, stream>>>(E1pad, e_w2, e_s2, e_b2, E2pad);
    conv_e3_mfma<<<dim3(72, 2, 8), blk, 0, stream>>>(E2pad, e_w3, e_s3, e_b3, E3pad);
    conv_e4_mfma<<<dim3(72, 2, 8), blk, 0, stream>>>(E3pad, e_w4, e_s4, e_b4, FL, FR);

    corr2_k<<<dim3(3, 96, 4), blk, 0, stream>>>(FL, FR, COST);

    zero_planes_k<<<dim3(75, 2, 2), blk, 0, stream>>>(C1pad, PB1E, P1E / 8, 49);
    halo2d_k<<<dim3(3, 1, 96), blk, 0, stream>>>(C1pad + P1E, PB1E, 48, P1E, 98, 194, 1);
    halo2d_k<<<dim3(5, 1, 96), blk, 0, stream>>>(C2pad + P2E, PB2E, 48, P2E, 98, 194, 2);

    // --- 3D aggregation: 2-batch super-batches, full-D, double-buffered ---
    for (int sb = 0; sb < 2; ++sb) {
        conv1_nhwc<<<dim3(18, 48, 2), blk, 0, stream>>>(
            COST + sb * 2 * DHW, a_w1, a_s1, a_b1, C1pad);
        conv2_mfma<<<dim3(288, 12, 2), blk, 0, stream>>>(
            C1pad, a_w2, a_s2, a_b2, C2pad);
        conv3_nhwc<<<dim3(36, 12, 2), blk, 0, stream>>>(
            C2pad, a_w3, C3 + sb * 2 * DHW);
    }

    softdisp_k<<<cdiv(4LL*H4*W4, 256), blk, 0, stream>>>(C3, DL, B, H4, W4);

    refine_fused<<<dim3(48, 24, 4), blk, 0, stream>>>(
        DL, r_w1, r_s1, r_b1, r_w2, out_disp);
}

// Round 21
// 403.538 us; speedup vs baseline: 1.0419x; 1.0419x over previous
//
#include <hip/hip_runtime.h>
#include <hip/hip_bf16.h>

typedef __hip_bfloat16 bf16;
typedef __attribute__((ext_vector_type(8))) short short8v;
typedef __attribute__((ext_vector_type(4))) float f32x4;

static inline int cdiv(long long a, int b){ return (int)((a + b - 1) / b); }

__device__ __forceinline__ float uaf(unsigned u){ return __uint_as_float(u); }
__device__ __forceinline__ float ldf(const bf16* p){ return __bfloat162float(*p); }
__device__ __forceinline__ void stf(bf16* p, float v){ *p = __float2bfloat16(v); }

__device__ __forceinline__ void load4v(const float* p, float& a, float& b, float& c, float& d){
    float4 v = *reinterpret_cast<const float4*>(p); a = v.x; b = v.y; c = v.z; d = v.w;
}
__device__ __forceinline__ unsigned short bfbits(float v){
    bf16 h = __float2bfloat16(v); unsigned short s; __builtin_memcpy(&s, &h, 2); return s;
}

// ====================== HALO ZEROING ======================
__global__ void halo2d_k(bf16* buf, long long bstride, int nsub, long long sstride,
                         int Hp, int Wp, int Cv)
{
    int z = blockIdx.z;
    bf16* b = buf + (long long)(z / nsub) * bstride + (long long)(z % nsub) * sstride;
    uint4 zz = make_uint4(0, 0, 0, 0);
    int rowV = Wp * Cv;
    int totalV = 2 * rowV + (Hp - 2) * 2 * Cv;
    for (int i = blockIdx.x * 256 + threadIdx.x; i < totalV; i += gridDim.x * 256) {
        long long off;
        if (i < rowV) off = i;
        else if (i < 2 * rowV) off = (long long)(Hp - 1) * rowV + (i - rowV);
        else {
            int k = i - 2 * rowV;
            int h = 1 + k / (2 * Cv);
            int r = k % (2 * Cv);
            int wc = (r < Cv) ? 0 : (Wp - 1);
            off = (long long)h * rowV + (long long)wc * Cv + (r < Cv ? r : r - Cv);
        }
        reinterpret_cast<uint4*>(b)[off] = zz;
    }
}

__global__ void zero_planes_k(bf16* buf, long long bstride, long long planeV, int lastPlane)
{
    int b = blockIdx.z, p = blockIdx.y;
    uint4 zz = make_uint4(0, 0, 0, 0);
    bf16* base = buf + (long long)b * bstride;
    long long pl = p ? (long long)lastPlane * planeV : 0;
    for (long long i = blockIdx.x * 256 + threadIdx.x; i < planeV; i += (long long)gridDim.x * 256)
        reinterpret_cast<uint4*>(base)[pl + i] = zz;
}

// ====================== ENCODER (NHWC bf16 chain) ======================
#define E12_BS 2396288LL   // bytes per img, 194*386*16*2
#define E3_BS  1216768LL   // 98*194*32*2

__global__ __launch_bounds__(256) void conv_e1(
    const float* __restrict__ in0, const float* __restrict__ in1,
    const float* __restrict__ w, const float* __restrict__ sc, const float* __restrict__ bi,
    bf16* __restrict__ out)
{
    const int H = 384, W = 768, NW = 96;
    int img = blockIdx.z;
    const float* in = (img >= 4) ? in1 + (long long)(img - 4) * 3 * 294912
                                 : in0 + (long long)img * 3 * 294912;

    __shared__ float wl[432];
    __shared__ float sl[16], bl[16];
    for (int j = threadIdx.x; j < 432; j += 256) {
        int k = j / 16, o = j % 16;
        wl[j] = w[o * 27 + k];
    }
    if (threadIdx.x < 16) { sl[threadIdx.x] = sc[threadIdx.x]; bl[threadIdx.x] = bi[threadIdx.x]; }
    __syncthreads();

    int unit = blockIdx.x * 256 + threadIdx.x;
    int h = unit / NW, wseg = unit % NW, w0 = wseg << 2;
    const long long HW = (long long)H * W;

    float acc[16][4];
#pragma unroll
    for (int o = 0; o < 16; ++o){ acc[o][0]=0.f; acc[o][1]=0.f; acc[o][2]=0.f; acc[o][3]=0.f; }

    for (int ic = 0; ic < 3; ++ic) {
        const float* ip = in + (long long)ic * HW;
#pragma unroll
        for (int kh = 0; kh < 3; ++kh) {
            int ih = 2 * h + kh - 1;
            if (ih < 0 || ih >= H) continue;
            const float* row = ip + (long long)ih * W;
            float x0,x1,x2,x3,x4,x5,x6,x7;
            load4v(row + 2 * w0,     x0, x1, x2, x3);
            load4v(row + 2 * w0 + 4, x4, x5, x6, x7);
            float xm = (w0 > 0) ? row[2 * w0 - 1] : 0.f;
            const float* wk = wl + (ic * 9 + kh * 3) * 16;
#pragma unroll
            for (int o = 0; o < 16; ++o) {
                float wa = wk[o], wb = wk[16 + o], wc = wk[32 + o];
                acc[o][0] = fmaf(xm, wa, fmaf(x0, wb, fmaf(x1, wc, acc[o][0])));
                acc[o][1] = fmaf(x1, wa, fmaf(x2, wb, fmaf(x3, wc, acc[o][1])));
                acc[o][2] = fmaf(x3, wa, fmaf(x4, wb, fmaf(x5, wc, acc[o][2])));
                acc[o][3] = fmaf(x5, wa, fmaf(x6, wb, fmaf(x7, wc, acc[o][3])));
            }
        }
    }
    char* ob = (char*)out + (long long)img * E12_BS;
#pragma unroll
    for (int i = 0; i < 4; ++i) {
        float v[16];
#pragma unroll
        for (int o = 0; o < 16; ++o) v[o] = fmaxf(acc[o][i] * sl[o] + bl[o], 0.f);
        uint4 u0, u1;
        u0.x = (unsigned)bfbits(v[0])  | ((unsigned)bfbits(v[1])  << 16);
        u0.y = (unsigned)bfbits(v[2])  | ((unsigned)bfbits(v[3])  << 16);
        u0.z = (unsigned)bfbits(v[4])  | ((unsigned)bfbits(v[5])  << 16);
        u0.w = (unsigned)bfbits(v[6])  | ((unsigned)bfbits(v[7])  << 16);
        u1.x = (unsigned)bfbits(v[8])  | ((unsigned)bfbits(v[9])  << 16);
        u1.y = (unsigned)bfbits(v[10]) | ((unsigned)bfbits(v[11]) << 16);
        u1.z = (unsigned)bfbits(v[12]) | ((unsigned)bfbits(v[13]) << 16);
        u1.w = (unsigned)bfbits(v[14]) | ((unsigned)bfbits(v[15]) << 16);
        char* p = ob + ((long long)(h + 1) * 386 + (w0 + i + 1)) * 32;
        *reinterpret_cast<uint4*>(p)      = u0;
        *reinterpret_cast<uint4*>(p + 16) = u1;
    }
}

__global__ __launch_bounds__(256) void conv_e2_mfma(
    const bf16* __restrict__ in, const float* __restrict__ w,
    const float* __restrict__ sc, const float* __restrict__ bi,
    bf16* __restrict__ out)
{
    __shared__ short alds[16 * 160];
    __shared__ int offl[20];
    int tid = threadIdx.x;
    for (int j = tid; j < 16 * 160; j += 256) {
        int oc = j / 160, kk = j % 160;
        short v = 0;
        if (kk < 144) { int tap = kk / 16, ic = kk % 16; v = (short)bfbits(w[oc * 144 + ic * 9 + tap]); }
        alds[j] = v;
    }
    if (tid < 20) {
        int c = tid / 4, g = tid % 4;
        int tap = 2 * c + (g >> 1); if (tap > 8) tap = 8;
        offl[tid] = ((tap / 3) * 386 + (tap % 3)) * 32 + (g & 1) * 16;
    }
    __syncthreads();

    int wid = tid >> 6, lane = tid & 63;
    int wt = blockIdx.x * 4 + wid;
    int h = wt / 6, w0 = (wt % 6) * 64;
    int img = blockIdx.z;
    int g = lane >> 4, px = lane & 15;

    const char* bp = (const char*)in + (long long)img * E12_BS
                   + ((long long)h * 386 + (w0 + px)) * 32;
    int offr[5];
#pragma unroll
    for (int c = 0; c < 5; ++c) offr[c] = offl[c * 4 + g];
    short8v af[5];
#pragma unroll
    for (int c = 0; c < 5; ++c)
        af[c] = *reinterpret_cast<const short8v*>(&alds[px * 160 + 32 * c + 8 * g]);

    f32x4 acc[4];
#pragma unroll
    for (int pg = 0; pg < 4; ++pg) {
        f32x4 a = {0.f, 0.f, 0.f, 0.f};
        const char* bpp = bp + pg * 512;
#pragma unroll
        for (int c = 0; c < 5; ++c) {
            short8v bf = *reinterpret_cast<const short8v*>(bpp + offr[c]);
            a = __builtin_amdgcn_mfma_f32_16x16x32_bf16(af[c], bf, a, 0, 0, 0);
        }
        acc[pg] = a;
    }
    char* ob = (char*)out + (long long)img * E12_BS;
#pragma unroll
    for (int pg = 0; pg < 4; ++pg) {
        float v[4];
#pragma unroll
        for (int r = 0; r < 4; ++r) {
            int oc = g * 4 + r;
            v[r] = fmaxf(acc[pg][r] * sc[oc] + bi[oc], 0.f);
        }
        uint2 u;
        u.x = (unsigned)bfbits(v[0]) | ((unsigned)bfbits(v[1]) << 16);
        u.y = (unsigned)bfbits(v[2]) | ((unsigned)bfbits(v[3]) << 16);
        *reinterpret_cast<uint2*>(ob + ((long long)(h + 1) * 386 + (w0 + pg * 16 + px + 1)) * 32 + g * 8) = u;
    }
}

__global__ __launch_bounds__(256) void conv_e3_mfma(
    const bf16* __restrict__ in, const float* __restrict__ w,
    const float* __restrict__ sc, const float* __restrict__ bi,
    bf16* __restrict__ out)
{
    __shared__ short alds[16 * 160];
    __shared__ int offl[20];
    int tid = threadIdx.x;
    int och = blockIdx.y;
    for (int j = tid; j < 16 * 160; j += 256) {
        int oc = j / 160, kk = j % 160;
        short v = 0;
        if (kk < 144) { int tap = kk / 16, ic = kk % 16; v = (short)bfbits(w[(och * 16 + oc) * 144 + ic * 9 + tap]); }
        alds[j] = v;
    }
    if (tid < 20) {
        int c = tid / 4, g = tid % 4;
        int tap = 2 * c + (g >> 1); if (tap > 8) tap = 8;
        offl[tid] = ((tap / 3) * 386 + (tap % 3)) * 32 + (g & 1) * 16;
    }
    __syncthreads();

    int wid = tid >> 6, lane = tid & 63;
    int wt = blockIdx.x * 4 + wid;
    int h = wt / 3, w0 = (wt % 3) * 64;
    int img = blockIdx.z;
    int g = lane >> 4, px = lane & 15;

    const char* bp = (const char*)in + (long long)img * E12_BS
                   + ((long long)(2 * h) * 386 + 2 * (w0 + px)) * 32;
    int offr[5];
#pragma unroll
    for (int c = 0; c < 5; ++c) offr[c] = offl[c * 4 + g];
    short8v af[5];
#pragma unroll
    for (int c = 0; c < 5; ++c)
        af[c] = *reinterpret_cast<const short8v*>(&alds[px * 160 + 32 * c + 8 * g]);

    f32x4 acc[4];
#pragma unroll
    for (int pg = 0; pg < 4; ++pg) {
        f32x4 a = {0.f, 0.f, 0.f, 0.f};
        const char* bpp = bp + pg * 1024;
#pragma unroll
        for (int c = 0; c < 5; ++c) {
            short8v bf = *reinterpret_cast<const short8v*>(bpp + offr[c]);
            a = __builtin_amdgcn_mfma_f32_16x16x32_bf16(af[c], bf, a, 0, 0, 0);
        }
        acc[pg] = a;
    }
    char* ob = (char*)out + (long long)img * E3_BS;
#pragma unroll
    for (int pg = 0; pg < 4; ++pg) {
        float v[4];
#pragma unroll
        for (int r = 0; r < 4; ++r) {
            int oc = och * 16 + g * 4 + r;
            v[r] = fmaxf(acc[pg][r] * sc[oc] + bi[oc], 0.f);
        }
        uint2 u;
        u.x = (unsigned)bfbits(v[0]) | ((unsigned)bfbits(v[1]) << 16);
        u.y = (unsigned)bfbits(v[2]) | ((unsigned)bfbits(v[3]) << 16);
        *reinterpret_cast<uint2*>(ob + ((long long)(h + 1) * 194 + (w0 + pg * 16 + px + 1)) * 64
                                  + och * 32 + g * 8) = u;
    }
}

__global__ __launch_bounds__(256) void conv_e4_mfma(
    const bf16* __restrict__ in, const float* __restrict__ w,
    const float* __restrict__ sc, const float* __restrict__ bi,
    float* __restrict__ fl, float* __restrict__ fr)
{
    __shared__ short alds[16 * 288];
    __shared__ int offl[36];
    int tid = threadIdx.x;
    int och = blockIdx.y;
    for (int j = tid; j < 16 * 288; j += 256) {
        int oc = j / 288, kk = j % 288;
        int tap = kk / 32, ic = kk % 32;
        alds[j] = (short)bfbits(w[(och * 16 + oc) * 288 + ic * 9 + tap]);
    }
    if (tid < 36) {
        int c = tid / 4, g = tid % 4;
        offl[tid] = ((c / 3) * 194 + (c % 3)) * 64 + g * 16;
    }
    __syncthreads();

    int wid = tid >> 6, lane = tid & 63;
    int wt = blockIdx.x * 4 + wid;
    int h = wt / 3, w0 = (wt % 3) * 64;
    int img = blockIdx.z;
    int g = lane >> 4, px = lane & 15;

    const char* bp = (const char*)in + (long long)img * E3_BS
                   + ((long long)h * 194 + (w0 + px)) * 64;
    int offr[9];
#pragma unroll
    for (int c = 0; c < 9; ++c) offr[c] = offl[c * 4 + g];
    short8v af[9];
#pragma unroll
    for (int c = 0; c < 9; ++c)
        af[c] = *reinterpret_cast<const short8v*>(&alds[px * 288 + 32 * c + 8 * g]);

    f32x4 acc[4];
#pragma unroll
    for (int pg = 0; pg < 4; ++pg) {
        f32x4 a = {0.f, 0.f, 0.f, 0.f};
        const char* bpp = bp + pg * 1024;
#pragma unroll
        for (int c = 0; c < 9; ++c) {
            short8v bf = *reinterpret_cast<const short8v*>(bpp + offr[c]);
            a = __builtin_amdgcn_mfma_f32_16x16x32_bf16(af[c], bf, a, 0, 0, 0);
        }
        acc[pg] = a;
    }
    float* dst = (img < 4) ? fl + (long long)img * 32 * 18432
                           : fr + (long long)(img - 4) * 32 * 18432;
#pragma unroll
    for (int pg = 0; pg < 4; ++pg) {
#pragma unroll
        for (int r = 0; r < 4; ++r) {
            int oc = och * 16 + g * 4 + r;
            float v = fmaxf(acc[pg][r] * sc[oc] + bi[oc], 0.f);
            dst[(long long)oc * 18432 + (long long)h * 192 + w0 + pg * 16 + px] = v;
        }
    }
}

// ====================== AGGREGATION ======================
#define PB1E 7604800LL     // C1pad elems per buffer (50*98*194*8)
#define PB2E 15209600LL    // C2pad elems per buffer (50*98*194*16)

__global__ __launch_bounds__(256) void conv1_nhwc(
    const float* __restrict__ in, const float* __restrict__ w,
    const float* __restrict__ sc, const float* __restrict__ bi,
    bf16* __restrict__ out)
{
    const int H = 96, W = 192, D = 48, NW = 48;
    int zb = blockIdx.z;
    const float* inz = in + (long long)zb * 884736;
    bf16* outz = out + (long long)zb * PB1E;
    int d = blockIdx.y;
    __shared__ float wl[216];
    __shared__ float sl[8], bl[8];
    for (int j = threadIdx.x; j < 216; j += 256) wl[j] = w[j];
    if (threadIdx.x < 8) { sl[threadIdx.x] = sc[threadIdx.x]; bl[threadIdx.x] = bi[threadIdx.x]; }
    __syncthreads();

    int unit = blockIdx.x * 256 + threadIdx.x;
    int h = unit / NW, wseg = unit % NW, w0 = wseg << 2;
    if (h >= H) return;

    float acc[8][4];
#pragma unroll
    for (int o = 0; o < 8; ++o){ acc[o][0]=0.f; acc[o][1]=0.f; acc[o][2]=0.f; acc[o][3]=0.f; }

#pragma unroll
    for (int kd = 0; kd < 3; ++kd) {
        int id = d + kd - 1;
        if (id < 0 || id >= D) continue;
        const float* plane = inz + (long long)id * H * W;
#pragma unroll
        for (int kh = 0; kh < 3; ++kh) {
            int ih = h + kh - 1;
            if (ih < 0 || ih >= H) continue;
            const float* row = plane + (long long)ih * W;
            float x0,x1,x2,x3;
            load4v(row + w0, x0, x1, x2, x3);
            float xl = (wseg > 0)      ? row[w0 - 1] : 0.f;
            float xr = (wseg < NW - 1) ? row[w0 + 4] : 0.f;
            int kb = kd * 9 + kh * 3;
#pragma unroll
            for (int o = 0; o < 8; ++o) {
                float wa = wl[o*27 + kb], wb = wl[o*27 + kb + 1], wc = wl[o*27 + kb + 2];
                acc[o][0] = fmaf(xl, wa, fmaf(x0, wb, fmaf(x1, wc, acc[o][0])));
                acc[o][1] = fmaf(x0, wa, fmaf(x1, wb, fmaf(x2, wc, acc[o][1])));
                acc[o][2] = fmaf(x1, wa, fmaf(x2, wb, fmaf(x3, wc, acc[o][2])));
                acc[o][3] = fmaf(x2, wa, fmaf(x3, wb, fmaf(xr, wc, acc[o][3])));
            }
        }
    }
#pragma unroll
    for (int i = 0; i < 4; ++i) {
        uint4 u;
        float v[8];
#pragma unroll
        for (int o = 0; o < 8; ++o) v[o] = fmaxf(acc[o][i] * sl[o] + bl[o], 0.f);
        u.x = (unsigned)bfbits(v[0]) | ((unsigned)bfbits(v[1]) << 16);
        u.y = (unsigned)bfbits(v[2]) | ((unsigned)bfbits(v[3]) << 16);
        u.z = (unsigned)bfbits(v[4]) | ((unsigned)bfbits(v[5]) << 16);
        u.w = (unsigned)bfbits(v[6]) | ((unsigned)bfbits(v[7]) << 16);
        long long idx = (((long long)(d + 1) * 98 + (h + 1)) * 194 + (w0 + 1 + i)) * 8;
        *reinterpret_cast<uint4*>(&outz[idx]) = u;
    }
}

__global__ __launch_bounds__(256) void conv2_mfma(
    const bf16* __restrict__ in, const float* __restrict__ w,
    const float* __restrict__ sc, const float* __restrict__ bi,
    bf16* __restrict__ out)
{
    __shared__ short alds[16 * 224];
    __shared__ uint4 sB[6 * 3 * 66];
    __shared__ int offl[28];
    int tid = threadIdx.x;
    int zb = blockIdx.z;
    const bf16* inz = in + (long long)zb * PB1E;
    for (int j = tid; j < 16 * 224; j += 256) {
        int oc = j / 224, kk = j % 224;
        short v = 0;
        if (kk < 216) { int t = kk / 8, ic = kk % 8; v = (short)bfbits(w[(oc * 8 + ic) * 27 + t]); }
        alds[j] = v;
    }
    if (tid < 28) {
        int t = (tid < 27) ? tid : 26;
        int kd = t / 9, kh = (t / 3) % 3, kw = t % 3;
        offl[tid] = (kd * 3 + kh) * 66 + kw;
    }

    int hw = blockIdx.x;
    int h = hw / 3, w0 = (hw % 3) * 64;
    int dq = blockIdx.y * 4;
    for (int j = tid; j < 1188; j += 256) {
        int p = j / 198, rem = j % 198;
        int r = rem / 66, c = rem % 66;
        sB[j] = *reinterpret_cast<const uint4*>(
            inz + (((long long)(dq + p) * 98 + (h + r)) * 194 + (w0 + c)) * 8);
    }
    __syncthreads();

    int wid = tid >> 6, lane = tid & 63;
    int g = lane >> 4, px = lane & 15;
    int d = dq + wid;

    const uint4* sBw = sB + wid * 198;
    int offr[7];
#pragma unroll
    for (int c = 0; c < 7; ++c) offr[c] = offl[4 * c + g];
    short8v af[7];
#pragma unroll
    for (int c = 0; c < 7; ++c)
        af[c] = *reinterpret_cast<const short8v*>(&alds[px * 224 + 32 * c + 8 * g]);

    f32x4 acc[4];
#pragma unroll
    for (int pg = 0; pg < 4; ++pg) {
        f32x4 a = {0.f, 0.f, 0.f, 0.f};
        int col = pg * 16 + px;
#pragma unroll
        for (int c = 0; c < 7; ++c) {
            short8v bf = *reinterpret_cast<const short8v*>(&sBw[offr[c] + col]);
            a = __builtin_amdgcn_mfma_f32_16x16x32_bf16(af[c], bf, a, 0, 0, 0);
        }
        acc[pg] = a;
    }

    char* ob = (char*)(out + (long long)zb * PB2E);
#pragma unroll
    for (int pg = 0; pg < 4; ++pg) {
        float v[4];
#pragma unroll
        for (int r = 0; r < 4; ++r) {
            int oc = g * 4 + r;
            v[r] = fmaxf(acc[pg][r] * sc[oc] + bi[oc], 0.f);
        }
        long long pxi = ((long long)(d + 1) * 98 + h + 1) * 194 + (w0 + pg * 16 + px + 1);
        uint2 u;
        u.x = (unsigned)bfbits(v[0]) | ((unsigned)bfbits(v[1]) << 16);
        u.y = (unsigned)bfbits(v[2]) | ((unsigned)bfbits(v[3]) << 16);
        *reinterpret_cast<uint2*>(ob + pxi * 32 + g * 8) = u;
    }
}

// ---- conv3 (16->1), DBLK=4 x 2 W-out/thread, ALL 4 batches in one launch.
// grid (36, 12, 4) = 1728 blocks (round-21: halve scheduling tail).
__global__ __launch_bounds__(256) void conv3_nhwc(
    const bf16* __restrict__ in, const float* __restrict__ w,
    float* __restrict__ out)
{
    const int H = 96, W = 192, D = 48, NW = 96;
    __shared__ float wl[27][16];
    for (int j = threadIdx.x; j < 432; j += 256) wl[j / 16][j % 16] = w[(j % 16) * 27 + j / 16];
    __syncthreads();

    int zb = blockIdx.z;
    const bf16* inz = in + (long long)zb * PB2E;
    float* outz = out + (long long)zb * 884736;
    int dl0 = blockIdx.y * 4;
    int unit = blockIdx.x * 256 + threadIdx.x;
    int h = unit / NW, wseg = unit % NW, w0 = wseg * 2;

    float acc[4][2];
#pragma unroll
    for (int o = 0; o < 4; ++o){ acc[o][0]=0.f; acc[o][1]=0.f; }

#pragma unroll
    for (int s = 0; s < 6; ++s) {
        int gid = dl0 - 1 + s;
        if (gid < 0 || gid >= D) continue;
        int il = gid + 1;
        const char* plane = (const char*)inz + (long long)il * 98 * 194 * 32;
#pragma unroll
        for (int kh = 0; kh < 3; ++kh) {
            const char* base = plane + ((long long)(h + kh) * 194 + w0) * 32;
#pragma unroll
            for (int hf = 0; hf < 2; ++hf) {
#pragma unroll
                for (int p = 0; p < 4; ++p) {
                    uint4 q = *reinterpret_cast<const uint4*>(base + p * 32 + hf * 16);
                    float x[8];
                    x[0]=uaf(q.x<<16); x[1]=uaf(q.x&0xffff0000u);
                    x[2]=uaf(q.y<<16); x[3]=uaf(q.y&0xffff0000u);
                    x[4]=uaf(q.z<<16); x[5]=uaf(q.z&0xffff0000u);
                    x[6]=uaf(q.w<<16); x[7]=uaf(q.w&0xffff0000u);
#pragma unroll
                    for (int o = 0; o < 4; ++o) {
                        int kd = s - o;
                        if (kd < 0 || kd > 2) continue;
#pragma unroll
                        for (int kw = 0; kw < 3; ++kw) {
                            int i = p - kw;
                            if (i < 0 || i > 1) continue;
                            const int t = kd * 9 + kh * 3 + kw;
                            float sum = 0.f;
#pragma unroll
                            for (int c = 0; c < 8; ++c) sum = fmaf(x[c], wl[t][hf * 8 + c], sum);
                            acc[o][i] += sum;
                        }
                    }
                }
            }
        }
    }
#pragma unroll
    for (int o = 0; o < 4; ++o) {
        float* op = outz + ((long long)(dl0 + o) * H + h) * W + w0;
        *reinterpret_cast<float2*>(op) = make_float2(acc[o][0], acc[o][1]);
    }
}

// ====================== REST ======================
__global__ __launch_bounds__(256) void corr2_k(
    const float* __restrict__ fl, const float* __restrict__ fr,
    float* __restrict__ cost)
{
    const int C = 32, D = 48, H = 96, W = 192;
    __shared__ float sfl[64 * 33];
    __shared__ float sfr[111 * 33];

    int w0 = blockIdx.x * 64, h = blockIdx.y, b = blockIdx.z;
    int tid = threadIdx.x;

    for (int j = tid; j < 64 * C; j += 256) {
        int w = j % 64, c = j / 64;
        sfl[w * 33 + c] = fl[(((long long)b * C + c) * H + h) * W + w0 + w];
    }
    for (int j = tid; j < 111 * C; j += 256) {
        int wp = j % 111, c = j / 111;
        int gw = w0 - 47 + wp;
        sfr[wp * 33 + c] = (gw >= 0) ? fr[(((long long)b * C + c) * H + h) * W + gw] : 0.f;
    }
    __syncthreads();

    int w = tid & 63, dg = tid >> 6;
    float flr[32];
#pragma unroll
    for (int c = 0; c < 32; ++c) flr[c] = sfl[w * 33 + c];

    for (int dd = 0; dd < 12; ++dd) {
        int d = dg * 12 + dd;
        int wi = w - d + 47;
        float a = 0.f;
#pragma unroll
        for (int c = 0; c < 32; ++c) a = fmaf(flr[c], sfr[wi * 33 + c], a);
        cost[(((long long)b * D + d) * H + h) * W + w0 + w] = a * (1.0f / 32.0f);
    }
}

__global__ void softdisp_k(const float* __restrict__ c3, float* __restrict__ dl,
                           int B, int H, int W)
{
    const int D = 48;
    long long idx = (long long)blockIdx.x * blockDim.x + threadIdx.x;
    long long total = (long long)B * H * W;
    if (idx >= total) return;
    int b = (int)(idx / ((long long)H * W));
    long long rem = idx % ((long long)H * W);
    const float* p = c3 + ((long long)b * D) * H * W + rem;
    long long st = (long long)H * W;

    float v[48];
    float mn = 1e30f;
#pragma unroll
    for (int d = 0; d < D; ++d) { v[d] = p[d * st]; mn = fminf(mn, v[d]); }
    float se = 0.f, sd = 0.f;
#pragma unroll
    for (int d = 0; d < D; ++d) {
        float e = expf(mn - v[d]);
        se += e;
        sd += e * (float)d;
    }
    dl[idx] = sd / se;
}

// ---- fused refinement with inline bilinear upsample from DL ----
__global__ __launch_bounds__(256) void refine_fused(
    const float* __restrict__ dlow, const float* __restrict__ w1,
    const float* __restrict__ s1, const float* __restrict__ b1,
    const float* __restrict__ w2, float* __restrict__ out)
{
    const int H = 384, W = 768, Hl = 96, Wl = 192;
    __shared__ float sdu[20][21];
    __shared__ float smid[18][18][20];
    __shared__ float w1l[144], s1l[16], b1l[16], w2l[144];
    int tid = threadIdx.x;
    if (tid < 144) {
        w1l[tid] = w1[tid];
        int ic = tid / 9, tap = tid % 9;
        w2l[tap * 16 + ic] = w2[tid];
    } else if (tid < 160) {
        s1l[tid - 144] = s1[tid - 144]; b1l[tid - 144] = b1[tid - 144];
    }

    int b = blockIdx.z, h0 = blockIdx.y * 16, w0 = blockIdx.x * 16;
    const float* dlb = dlow + (long long)b * Hl * Wl;
    for (int j = tid; j < 400; j += 256) {
        int i = j / 20, k = j % 20;
        int y = h0 - 2 + i, x = w0 - 2 + k;
        float v = 0.f;
        if (y >= 0 && y < H && x >= 0 && x < W) {
            float sy = (y + 0.5f) * 0.25f - 0.5f;
            float sx = (x + 0.5f) * 0.25f - 0.5f;
            sy = fminf(fmaxf(sy, 0.f), (float)(Hl - 1));
            sx = fminf(fmaxf(sx, 0.f), (float)(Wl - 1));
            int y0 = (int)sy, x0 = (int)sx;
            int y1 = min(y0 + 1, Hl - 1), x1 = min(x0 + 1, Wl - 1);
            float fy = sy - y0, fx = sx - x0;
            v = 4.0f * ((1.f - fy) * ((1.f - fx) * dlb[y0 * Wl + x0] + fx * dlb[y0 * Wl + x1])
                      +        fy  * ((1.f - fx) * dlb[y1 * Wl + x0] + fx * dlb[y1 * Wl + x1]));
        }
        sdu[i][k] = v;
    }
    __syncthreads();

    for (int idx = tid; idx < 324; idx += 256) {
        int i = idx / 18, j = idx % 18;
        int gy = h0 - 1 + i, gx = w0 - 1 + j;
        bool inimg = (gy >= 0 && gy < H && gx >= 0 && gx < W);
        float t[9];
#pragma unroll
        for (int kh = 0; kh < 3; ++kh)
#pragma unroll
            for (int kw = 0; kw < 3; ++kw) t[kh * 3 + kw] = sdu[i + kh][j + kw];
        float m[16];
#pragma unroll
        for (int oc = 0; oc < 16; ++oc) {
            float s = 0.f;
#pragma unroll
            for (int k = 0; k < 9; ++k) s = fmaf(t[k], w1l[oc * 9 + k], s);
            m[oc] = inimg ? fmaxf(s * s1l[oc] + b1l[oc], 0.f) : 0.f;
        }
#pragma unroll
        for (int q = 0; q < 4; ++q)
            *reinterpret_cast<float4*>(&smid[i][j][q * 4]) =
                make_float4(m[q*4], m[q*4+1], m[q*4+2], m[q*4+3]);
    }
    __syncthreads();

    int i = tid >> 4, j = tid & 15;
    float s = 0.f;
#pragma unroll
    for (int kh = 0; kh < 3; ++kh)
#pragma unroll
        for (int kw = 0; kw < 3; ++kw) {
            const float* mp = &smid[i + kh][j + kw][0];
            const float* wp = &w2l[(kh * 3 + kw) * 16];
#pragma unroll
            for (int q = 0; q < 4; ++q) {
                float4 x = *reinterpret_cast<const float4*>(mp + q * 4);
                s = fmaf(x.x, wp[q*4+0], s);
                s = fmaf(x.y, wp[q*4+1], s);
                s = fmaf(x.z, wp[q*4+2], s);
                s = fmaf(x.w, wp[q*4+3], s);
            }
        }
    out[(long long)b * H * W + (long long)(h0 + i) * W + w0 + j] = fmaxf(s, 0.f);
}

extern "C" void kernel_launch(void* const* d_in, const int* in_sizes, int n_in,
                              void* d_out, int out_size, void* d_ws, size_t ws_size,
                              hipStream_t stream)
{
    const float* img_l = (const float*)d_in[0];
    const float* img_r = (const float*)d_in[1];
    const float* e_w1 = (const float*)d_in[2];
    const float* e_w2 = (const float*)d_in[3];
    const float* e_w3 = (const float*)d_in[4];
    const float* e_w4 = (const float*)d_in[5];
    const float* e_s1 = (const float*)d_in[6];
    const float* e_s2 = (const float*)d_in[7];
    const float* e_s3 = (const float*)d_in[8];
    const float* e_s4 = (const float*)d_in[9];
    const float* e_b1 = (const float*)d_in[10];
    const float* e_b2 = (const float*)d_in[11];
    const float* e_b3 = (const float*)d_in[12];
    const float* e_b4 = (const float*)d_in[13];
    const float* a_w1 = (const float*)d_in[14];
    const float* a_s1 = (const float*)d_in[15];
    const float* a_b1 = (const float*)d_in[16];
    const float* a_w2 = (const float*)d_in[17];
    const float* a_s2 = (const float*)d_in[18];
    const float* a_b2 = (const float*)d_in[19];
    const float* a_w3 = (const float*)d_in[20];
    const float* r_w1 = (const float*)d_in[21];
    const float* r_s1 = (const float*)d_in[22];
    const float* r_b1 = (const float*)d_in[23];
    const float* r_w2 = (const float*)d_in[24];

    const int B = 4, H = 384, W = 768, H4 = 96, W4 = 192, D = 48;
    const long long HW4 = (long long)H4 * W4;
    const long long DHW = (long long)D * HW4;
    const long long E12E = E12_BS / 2;
    const long long P1E = 98LL * 194 * 8;
    const long long P2E = 98LL * 194 * 16;

    float* out_disp = (float*)d_out;
    float* FL       = out_disp + 1179648;

    // ---- workspace layout (peak 166.6 MB; round-21: 4 C2 buffers, deferred conv3) ----
    char* ws = (char*)d_ws;
    bf16*  E1pad = (bf16*)(ws + 0);             // 19,170,304
    bf16*  E2pad = (bf16*)(ws + 19170304);      // 19,170,304
    bf16*  E3pad = (bf16*)(ws + 38340608);      //  9,734,144
    float* FR    = (float*)(ws + 48074752);     //  9,437,184 (dead after corr)
    float* COST  = (float*)(ws + 0);            // 14,155,776 (E1 region)
    bf16*  C1pad = (bf16*) (ws + 14155776);     // 2 x 15,209,600 (ends 44,574,976)
    bf16*  C2pad = (bf16*) (ws + 44574976);     // 4 x 30,419,200 (ends 166,251,776)
    float* C3    = COST;
    float* DL    = (float*)(ws + 166251776);    //    294,912 (ends 166,546,688)

    dim3 blk(256);

    halo2d_k<<<dim3(10, 1, 16), blk, 0, stream>>>(E1pad, E12E, 1, 0, 194, 386, 2);
    halo2d_k<<<dim3(10, 1, 8),  blk, 0, stream>>>(E3pad, E3_BS / 2, 1, 0, 98, 194, 4);

    conv_e1<<<dim3(72, 1, 8), blk, 0, stream>>>(img_l, img_r, e_w1, e_s1, e_b1, E1pad);
    conv_e2_mfma<<<dim3(288, 1, 8), blk, 0, stream>>>(E1pad, e_w2, e_s2, e_b2, E2pad);
    conv_e3_mfma<<<dim3(72, 2, 8), blk, 0, stream>>>(E2pad, e_w3, e_s3, e_b3, E3pad);
    conv_e4_mfma<<<dim3(72, 2, 8), blk, 0, stream>>>(E3pad, e_w4, e_s4, e_b4, FL, FR);

    corr2_k<<<dim3(3, 96, 4), blk, 0, stream>>>(FL, FR, COST);

    // halo zeroing: C1 (2 buffers), C2 (4 buffers)
    zero_planes_k<<<dim3(75, 2, 2), blk, 0, stream>>>(C1pad, PB1E, P1E / 8, 49);
    halo2d_k<<<dim3(3, 1, 96), blk, 0, stream>>>(C1pad + P1E, PB1E, 48, P1E, 98, 194, 1);
    halo2d_k<<<dim3(5, 1, 192), blk, 0, stream>>>(C2pad + P2E, PB2E, 48, P2E, 98, 194, 2);

    // --- conv1+conv2 per super-batch (2-buffer C1), conv2 fills C2 buffers sb*2, sb*2+1 ---
    for (int sb = 0; sb < 2; ++sb) {
        conv1_nhwc<<<dim3(18, 48, 2), blk, 0, stream>>>(
            COST + sb * 2 * DHW, a_w1, a_s1, a_b1, C1pad);
        conv2_mfma<<<dim3(288, 12, 2), blk, 0, stream>>>(
            C1pad, a_w2, a_s2, a_b2, C2pad + sb * 2 * PB2E);
    }

    // --- conv3: all 4 batches, one launch (1728 blocks) ---
    conv3_nhwc<<<dim3(36, 12, 4), blk, 0, stream>>>(C2pad, a_w3, C3);

    softdisp_k<<<cdiv(4LL*H4*W4, 256), blk, 0, stream>>>(C3, DL, B, H4, W4);

    refine_fused<<<dim3(48, 24, 4), blk, 0, stream>>>(
        DL, r_w1, r_s1, r_b1, r_w2, out_disp);
}

// Round 22
// 394.342 us; speedup vs baseline: 1.0662x; 1.0233x over previous
//
#include <hip/hip_runtime.h>
#include <hip/hip_bf16.h>

typedef __hip_bfloat16 bf16;
typedef __attribute__((ext_vector_type(8))) short short8v;
typedef __attribute__((ext_vector_type(4))) float f32x4;

static inline int cdiv(long long a, int b){ return (int)((a + b - 1) / b); }

__device__ __forceinline__ float uaf(unsigned u){ return __uint_as_float(u); }
__device__ __forceinline__ float ldf(const bf16* p){ return __bfloat162float(*p); }
__device__ __forceinline__ void stf(bf16* p, float v){ *p = __float2bfloat16(v); }

__device__ __forceinline__ void load4v(const float* p, float& a, float& b, float& c, float& d){
    float4 v = *reinterpret_cast<const float4*>(p); a = v.x; b = v.y; c = v.z; d = v.w;
}
__device__ __forceinline__ unsigned short bfbits(float v){
    bf16 h = __float2bfloat16(v); unsigned short s; __builtin_memcpy(&s, &h, 2); return s;
}

// ====================== HALO ZEROING ======================
__global__ void halo2d_k(bf16* buf, long long bstride, int nsub, long long sstride,
                         int Hp, int Wp, int Cv)
{
    int z = blockIdx.z;
    bf16* b = buf + (long long)(z / nsub) * bstride + (long long)(z % nsub) * sstride;
    uint4 zz = make_uint4(0, 0, 0, 0);
    int rowV = Wp * Cv;
    int totalV = 2 * rowV + (Hp - 2) * 2 * Cv;
    for (int i = blockIdx.x * 256 + threadIdx.x; i < totalV; i += gridDim.x * 256) {
        long long off;
        if (i < rowV) off = i;
        else if (i < 2 * rowV) off = (long long)(Hp - 1) * rowV + (i - rowV);
        else {
            int k = i - 2 * rowV;
            int h = 1 + k / (2 * Cv);
            int r = k % (2 * Cv);
            int wc = (r < Cv) ? 0 : (Wp - 1);
            off = (long long)h * rowV + (long long)wc * Cv + (r < Cv ? r : r - Cv);
        }
        reinterpret_cast<uint4*>(b)[off] = zz;
    }
}

__global__ void zero_planes_k(bf16* buf, long long bstride, long long planeV, int lastPlane)
{
    int b = blockIdx.z, p = blockIdx.y;
    uint4 zz = make_uint4(0, 0, 0, 0);
    bf16* base = buf + (long long)b * bstride;
    long long pl = p ? (long long)lastPlane * planeV : 0;
    for (long long i = blockIdx.x * 256 + threadIdx.x; i < planeV; i += (long long)gridDim.x * 256)
        reinterpret_cast<uint4*>(base)[pl + i] = zz;
}

// ====================== ENCODER (NHWC bf16 chain) ======================
#define E12_BS 2396288LL   // bytes per img, 194*386*16*2
#define E3_BS  1216768LL   // 98*194*32*2

__global__ __launch_bounds__(256) void conv_e1(
    const float* __restrict__ in0, const float* __restrict__ in1,
    const float* __restrict__ w, const float* __restrict__ sc, const float* __restrict__ bi,
    bf16* __restrict__ out)
{
    const int H = 384, W = 768, NW = 96;
    int img = blockIdx.z;
    const float* in = (img >= 4) ? in1 + (long long)(img - 4) * 3 * 294912
                                 : in0 + (long long)img * 3 * 294912;

    __shared__ float wl[432];
    __shared__ float sl[16], bl[16];
    for (int j = threadIdx.x; j < 432; j += 256) {
        int k = j / 16, o = j % 16;
        wl[j] = w[o * 27 + k];
    }
    if (threadIdx.x < 16) { sl[threadIdx.x] = sc[threadIdx.x]; bl[threadIdx.x] = bi[threadIdx.x]; }
    __syncthreads();

    int unit = blockIdx.x * 256 + threadIdx.x;
    int h = unit / NW, wseg = unit % NW, w0 = wseg << 2;
    const long long HW = (long long)H * W;

    float acc[16][4];
#pragma unroll
    for (int o = 0; o < 16; ++o){ acc[o][0]=0.f; acc[o][1]=0.f; acc[o][2]=0.f; acc[o][3]=0.f; }

    for (int ic = 0; ic < 3; ++ic) {
        const float* ip = in + (long long)ic * HW;
#pragma unroll
        for (int kh = 0; kh < 3; ++kh) {
            int ih = 2 * h + kh - 1;
            if (ih < 0 || ih >= H) continue;
            const float* row = ip + (long long)ih * W;
            float x0,x1,x2,x3,x4,x5,x6,x7;
            load4v(row + 2 * w0,     x0, x1, x2, x3);
            load4v(row + 2 * w0 + 4, x4, x5, x6, x7);
            float xm = (w0 > 0) ? row[2 * w0 - 1] : 0.f;
            const float* wk = wl + (ic * 9 + kh * 3) * 16;
#pragma unroll
            for (int o = 0; o < 16; ++o) {
                float wa = wk[o], wb = wk[16 + o], wc = wk[32 + o];
                acc[o][0] = fmaf(xm, wa, fmaf(x0, wb, fmaf(x1, wc, acc[o][0])));
                acc[o][1] = fmaf(x1, wa, fmaf(x2, wb, fmaf(x3, wc, acc[o][1])));
                acc[o][2] = fmaf(x3, wa, fmaf(x4, wb, fmaf(x5, wc, acc[o][2])));
                acc[o][3] = fmaf(x5, wa, fmaf(x6, wb, fmaf(x7, wc, acc[o][3])));
            }
        }
    }
    char* ob = (char*)out + (long long)img * E12_BS;
#pragma unroll
    for (int i = 0; i < 4; ++i) {
        float v[16];
#pragma unroll
        for (int o = 0; o < 16; ++o) v[o] = fmaxf(acc[o][i] * sl[o] + bl[o], 0.f);
        uint4 u0, u1;
        u0.x = (unsigned)bfbits(v[0])  | ((unsigned)bfbits(v[1])  << 16);
        u0.y = (unsigned)bfbits(v[2])  | ((unsigned)bfbits(v[3])  << 16);
        u0.z = (unsigned)bfbits(v[4])  | ((unsigned)bfbits(v[5])  << 16);
        u0.w = (unsigned)bfbits(v[6])  | ((unsigned)bfbits(v[7])  << 16);
        u1.x = (unsigned)bfbits(v[8])  | ((unsigned)bfbits(v[9])  << 16);
        u1.y = (unsigned)bfbits(v[10]) | ((unsigned)bfbits(v[11]) << 16);
        u1.z = (unsigned)bfbits(v[12]) | ((unsigned)bfbits(v[13]) << 16);
        u1.w = (unsigned)bfbits(v[14]) | ((unsigned)bfbits(v[15]) << 16);
        char* p = ob + ((long long)(h + 1) * 386 + (w0 + i + 1)) * 32;
        *reinterpret_cast<uint4*>(p)      = u0;
        *reinterpret_cast<uint4*>(p + 16) = u1;
    }
}

__global__ __launch_bounds__(256) void conv_e2_mfma(
    const bf16* __restrict__ in, const float* __restrict__ w,
    const float* __restrict__ sc, const float* __restrict__ bi,
    bf16* __restrict__ out)
{
    __shared__ short alds[16 * 160];
    __shared__ int offl[20];
    int tid = threadIdx.x;
    for (int j = tid; j < 16 * 160; j += 256) {
        int oc = j / 160, kk = j % 160;
        short v = 0;
        if (kk < 144) { int tap = kk / 16, ic = kk % 16; v = (short)bfbits(w[oc * 144 + ic * 9 + tap]); }
        alds[j] = v;
    }
    if (tid < 20) {
        int c = tid / 4, g = tid % 4;
        int tap = 2 * c + (g >> 1); if (tap > 8) tap = 8;
        offl[tid] = ((tap / 3) * 386 + (tap % 3)) * 32 + (g & 1) * 16;
    }
    __syncthreads();

    int wid = tid >> 6, lane = tid & 63;
    int wt = blockIdx.x * 4 + wid;
    int h = wt / 6, w0 = (wt % 6) * 64;
    int img = blockIdx.z;
    int g = lane >> 4, px = lane & 15;

    const char* bp = (const char*)in + (long long)img * E12_BS
                   + ((long long)h * 386 + (w0 + px)) * 32;
    int offr[5];
#pragma unroll
    for (int c = 0; c < 5; ++c) offr[c] = offl[c * 4 + g];
    short8v af[5];
#pragma unroll
    for (int c = 0; c < 5; ++c)
        af[c] = *reinterpret_cast<const short8v*>(&alds[px * 160 + 32 * c + 8 * g]);

    f32x4 acc[4];
#pragma unroll
    for (int pg = 0; pg < 4; ++pg) {
        f32x4 a = {0.f, 0.f, 0.f, 0.f};
        const char* bpp = bp + pg * 512;
#pragma unroll
        for (int c = 0; c < 5; ++c) {
            short8v bf = *reinterpret_cast<const short8v*>(bpp + offr[c]);
            a = __builtin_amdgcn_mfma_f32_16x16x32_bf16(af[c], bf, a, 0, 0, 0);
        }
        acc[pg] = a;
    }
    char* ob = (char*)out + (long long)img * E12_BS;
#pragma unroll
    for (int pg = 0; pg < 4; ++pg) {
        float v[4];
#pragma unroll
        for (int r = 0; r < 4; ++r) {
            int oc = g * 4 + r;
            v[r] = fmaxf(acc[pg][r] * sc[oc] + bi[oc], 0.f);
        }
        uint2 u;
        u.x = (unsigned)bfbits(v[0]) | ((unsigned)bfbits(v[1]) << 16);
        u.y = (unsigned)bfbits(v[2]) | ((unsigned)bfbits(v[3]) << 16);
        *reinterpret_cast<uint2*>(ob + ((long long)(h + 1) * 386 + (w0 + pg * 16 + px + 1)) * 32 + g * 8) = u;
    }
}

__global__ __launch_bounds__(256) void conv_e3_mfma(
    const bf16* __restrict__ in, const float* __restrict__ w,
    const float* __restrict__ sc, const float* __restrict__ bi,
    bf16* __restrict__ out)
{
    __shared__ short alds[16 * 160];
    __shared__ int offl[20];
    int tid = threadIdx.x;
    int och = blockIdx.y;
    for (int j = tid; j < 16 * 160; j += 256) {
        int oc = j / 160, kk = j % 160;
        short v = 0;
        if (kk < 144) { int tap = kk / 16, ic = kk % 16; v = (short)bfbits(w[(och * 16 + oc) * 144 + ic * 9 + tap]); }
        alds[j] = v;
    }
    if (tid < 20) {
        int c = tid / 4, g = tid % 4;
        int tap = 2 * c + (g >> 1); if (tap > 8) tap = 8;
        offl[tid] = ((tap / 3) * 386 + (tap % 3)) * 32 + (g & 1) * 16;
    }
    __syncthreads();

    int wid = tid >> 6, lane = tid & 63;
    int wt = blockIdx.x * 4 + wid;
    int h = wt / 3, w0 = (wt % 3) * 64;
    int img = blockIdx.z;
    int g = lane >> 4, px = lane & 15;

    const char* bp = (const char*)in + (long long)img * E12_BS
                   + ((long long)(2 * h) * 386 + 2 * (w0 + px)) * 32;
    int offr[5];
#pragma unroll
    for (int c = 0; c < 5; ++c) offr[c] = offl[c * 4 + g];
    short8v af[5];
#pragma unroll
    for (int c = 0; c < 5; ++c)
        af[c] = *reinterpret_cast<const short8v*>(&alds[px * 160 + 32 * c + 8 * g]);

    f32x4 acc[4];
#pragma unroll
    for (int pg = 0; pg < 4; ++pg) {
        f32x4 a = {0.f, 0.f, 0.f, 0.f};
        const char* bpp = bp + pg * 1024;
#pragma unroll
        for (int c = 0; c < 5; ++c) {
            short8v bf = *reinterpret_cast<const short8v*>(bpp + offr[c]);
            a = __builtin_amdgcn_mfma_f32_16x16x32_bf16(af[c], bf, a, 0, 0, 0);
        }
        acc[pg] = a;
    }
    char* ob = (char*)out + (long long)img * E3_BS;
#pragma unroll
    for (int pg = 0; pg < 4; ++pg) {
        float v[4];
#pragma unroll
        for (int r = 0; r < 4; ++r) {
            int oc = och * 16 + g * 4 + r;
            v[r] = fmaxf(acc[pg][r] * sc[oc] + bi[oc], 0.f);
        }
        uint2 u;
        u.x = (unsigned)bfbits(v[0]) | ((unsigned)bfbits(v[1]) << 16);
        u.y = (unsigned)bfbits(v[2]) | ((unsigned)bfbits(v[3]) << 16);
        *reinterpret_cast<uint2*>(ob + ((long long)(h + 1) * 194 + (w0 + pg * 16 + px + 1)) * 64
                                  + och * 32 + g * 8) = u;
    }
}

__global__ __launch_bounds__(256) void conv_e4_mfma(
    const bf16* __restrict__ in, const float* __restrict__ w,
    const float* __restrict__ sc, const float* __restrict__ bi,
    float* __restrict__ fl, float* __restrict__ fr)
{
    __shared__ short alds[16 * 288];
    __shared__ int offl[36];
    int tid = threadIdx.x;
    int och = blockIdx.y;
    for (int j = tid; j < 16 * 288; j += 256) {
        int oc = j / 288, kk = j % 288;
        int tap = kk / 32, ic = kk % 32;
        alds[j] = (short)bfbits(w[(och * 16 + oc) * 288 + ic * 9 + tap]);
    }
    if (tid < 36) {
        int c = tid / 4, g = tid % 4;
        offl[tid] = ((c / 3) * 194 + (c % 3)) * 64 + g * 16;
    }
    __syncthreads();

    int wid = tid >> 6, lane = tid & 63;
    int wt = blockIdx.x * 4 + wid;
    int h = wt / 3, w0 = (wt % 3) * 64;
    int img = blockIdx.z;
    int g = lane >> 4, px = lane & 15;

    const char* bp = (const char*)in + (long long)img * E3_BS
                   + ((long long)h * 194 + (w0 + px)) * 64;
    int offr[9];
#pragma unroll
    for (int c = 0; c < 9; ++c) offr[c] = offl[c * 4 + g];
    short8v af[9];
#pragma unroll
    for (int c = 0; c < 9; ++c)
        af[c] = *reinterpret_cast<const short8v*>(&alds[px * 288 + 32 * c + 8 * g]);

    f32x4 acc[4];
#pragma unroll
    for (int pg = 0; pg < 4; ++pg) {
        f32x4 a = {0.f, 0.f, 0.f, 0.f};
        const char* bpp = bp + pg * 1024;
#pragma unroll
        for (int c = 0; c < 9; ++c) {
            short8v bf = *reinterpret_cast<const short8v*>(bpp + offr[c]);
            a = __builtin_amdgcn_mfma_f32_16x16x32_bf16(af[c], bf, a, 0, 0, 0);
        }
        acc[pg] = a;
    }
    float* dst = (img < 4) ? fl + (long long)img * 32 * 18432
                           : fr + (long long)(img - 4) * 32 * 18432;
#pragma unroll
    for (int pg = 0; pg < 4; ++pg) {
#pragma unroll
        for (int r = 0; r < 4; ++r) {
            int oc = och * 16 + g * 4 + r;
            float v = fmaxf(acc[pg][r] * sc[oc] + bi[oc], 0.f);
            dst[(long long)oc * 18432 + (long long)h * 192 + w0 + pg * 16 + px] = v;
        }
    }
}

// ====================== AGGREGATION ======================
#define PB1E 7604800LL     // C1pad elems per buffer (50*98*194*8)
#define PB2E 15209600LL    // C2pad elems per buffer (50*98*194*16)

__global__ __launch_bounds__(256) void conv1_nhwc(
    const float* __restrict__ in, const float* __restrict__ w,
    const float* __restrict__ sc, const float* __restrict__ bi,
    bf16* __restrict__ out)
{
    const int H = 96, W = 192, D = 48, NW = 48;
    int zb = blockIdx.z;
    const float* inz = in + (long long)zb * 884736;
    bf16* outz = out + (long long)zb * PB1E;
    int d = blockIdx.y;
    __shared__ float wl[216];
    __shared__ float sl[8], bl[8];
    for (int j = threadIdx.x; j < 216; j += 256) wl[j] = w[j];
    if (threadIdx.x < 8) { sl[threadIdx.x] = sc[threadIdx.x]; bl[threadIdx.x] = bi[threadIdx.x]; }
    __syncthreads();

    int unit = blockIdx.x * 256 + threadIdx.x;
    int h = unit / NW, wseg = unit % NW, w0 = wseg << 2;
    if (h >= H) return;

    float acc[8][4];
#pragma unroll
    for (int o = 0; o < 8; ++o){ acc[o][0]=0.f; acc[o][1]=0.f; acc[o][2]=0.f; acc[o][3]=0.f; }

#pragma unroll
    for (int kd = 0; kd < 3; ++kd) {
        int id = d + kd - 1;
        if (id < 0 || id >= D) continue;
        const float* plane = inz + (long long)id * H * W;
#pragma unroll
        for (int kh = 0; kh < 3; ++kh) {
            int ih = h + kh - 1;
            if (ih < 0 || ih >= H) continue;
            const float* row = plane + (long long)ih * W;
            float x0,x1,x2,x3;
            load4v(row + w0, x0, x1, x2, x3);
            float xl = (wseg > 0)      ? row[w0 - 1] : 0.f;
            float xr = (wseg < NW - 1) ? row[w0 + 4] : 0.f;
            int kb = kd * 9 + kh * 3;
#pragma unroll
            for (int o = 0; o < 8; ++o) {
                float wa = wl[o*27 + kb], wb = wl[o*27 + kb + 1], wc = wl[o*27 + kb + 2];
                acc[o][0] = fmaf(xl, wa, fmaf(x0, wb, fmaf(x1, wc, acc[o][0])));
                acc[o][1] = fmaf(x0, wa, fmaf(x1, wb, fmaf(x2, wc, acc[o][1])));
                acc[o][2] = fmaf(x1, wa, fmaf(x2, wb, fmaf(x3, wc, acc[o][2])));
                acc[o][3] = fmaf(x2, wa, fmaf(x3, wb, fmaf(xr, wc, acc[o][3])));
            }
        }
    }
#pragma unroll
    for (int i = 0; i < 4; ++i) {
        uint4 u;
        float v[8];
#pragma unroll
        for (int o = 0; o < 8; ++o) v[o] = fmaxf(acc[o][i] * sl[o] + bl[o], 0.f);
        u.x = (unsigned)bfbits(v[0]) | ((unsigned)bfbits(v[1]) << 16);
        u.y = (unsigned)bfbits(v[2]) | ((unsigned)bfbits(v[3]) << 16);
        u.z = (unsigned)bfbits(v[4]) | ((unsigned)bfbits(v[5]) << 16);
        u.w = (unsigned)bfbits(v[6]) | ((unsigned)bfbits(v[7]) << 16);
        long long idx = (((long long)(d + 1) * 98 + (h + 1)) * 194 + (w0 + 1 + i)) * 8;
        *reinterpret_cast<uint4*>(&outz[idx]) = u;
    }
}

__global__ __launch_bounds__(256) void conv2_mfma(
    const bf16* __restrict__ in, const float* __restrict__ w,
    const float* __restrict__ sc, const float* __restrict__ bi,
    bf16* __restrict__ out)
{
    __shared__ short alds[16 * 224];
    __shared__ uint4 sB[6 * 3 * 66];
    __shared__ int offl[28];
    int tid = threadIdx.x;
    int zb = blockIdx.z;
    const bf16* inz = in + (long long)zb * PB1E;
    for (int j = tid; j < 16 * 224; j += 256) {
        int oc = j / 224, kk = j % 224;
        short v = 0;
        if (kk < 216) { int t = kk / 8, ic = kk % 8; v = (short)bfbits(w[(oc * 8 + ic) * 27 + t]); }
        alds[j] = v;
    }
    if (tid < 28) {
        int t = (tid < 27) ? tid : 26;
        int kd = t / 9, kh = (t / 3) % 3, kw = t % 3;
        offl[tid] = (kd * 3 + kh) * 66 + kw;
    }

    int hw = blockIdx.x;
    int h = hw / 3, w0 = (hw % 3) * 64;
    int dq = blockIdx.y * 4;
    for (int j = tid; j < 1188; j += 256) {
        int p = j / 198, rem = j % 198;
        int r = rem / 66, c = rem % 66;
        sB[j] = *reinterpret_cast<const uint4*>(
            inz + (((long long)(dq + p) * 98 + (h + r)) * 194 + (w0 + c)) * 8);
    }
    __syncthreads();

    int wid = tid >> 6, lane = tid & 63;
    int g = lane >> 4, px = lane & 15;
    int d = dq + wid;

    const uint4* sBw = sB + wid * 198;
    int offr[7];
#pragma unroll
    for (int c = 0; c < 7; ++c) offr[c] = offl[4 * c + g];
    short8v af[7];
#pragma unroll
    for (int c = 0; c < 7; ++c)
        af[c] = *reinterpret_cast<const short8v*>(&alds[px * 224 + 32 * c + 8 * g]);

    f32x4 acc[4];
#pragma unroll
    for (int pg = 0; pg < 4; ++pg) {
        f32x4 a = {0.f, 0.f, 0.f, 0.f};
        int col = pg * 16 + px;
#pragma unroll
        for (int c = 0; c < 7; ++c) {
            short8v bf = *reinterpret_cast<const short8v*>(&sBw[offr[c] + col]);
            a = __builtin_amdgcn_mfma_f32_16x16x32_bf16(af[c], bf, a, 0, 0, 0);
        }
        acc[pg] = a;
    }

    char* ob = (char*)(out + (long long)zb * PB2E);
#pragma unroll
    for (int pg = 0; pg < 4; ++pg) {
        float v[4];
#pragma unroll
        for (int r = 0; r < 4; ++r) {
            int oc = g * 4 + r;
            v[r] = fmaxf(acc[pg][r] * sc[oc] + bi[oc], 0.f);
        }
        long long pxi = ((long long)(d + 1) * 98 + h + 1) * 194 + (w0 + pg * 16 + px + 1);
        uint2 u;
        u.x = (unsigned)bfbits(v[0]) | ((unsigned)bfbits(v[1]) << 16);
        u.y = (unsigned)bfbits(v[2]) | ((unsigned)bfbits(v[3]) << 16);
        *reinterpret_cast<uint2*>(ob + pxi * 32 + g * 8) = u;
    }
}

// ---- conv3 (16->1) via MFMA, M=1 row (round-22). in: padded NHWC16 C2.
// A = a_w3 as K=(tap,ch) row 0 (rows 1-15 zero); B = LDS-staged im2col.
// grid (288, 12, 4): hw tile, dq = by*4 (wave wid -> d = dq+wid), batch z.
__global__ __launch_bounds__(256) void conv3_mfma(
    const bf16* __restrict__ in, const float* __restrict__ w,
    float* __restrict__ out)
{
    __shared__ uint4 sB[6 * 3 * 66 * 2];     // 6 planes x 3 rows x 66 px x 16ch (38016 B)
    __shared__ short wlds[448] __attribute__((aligned(16)));
    __shared__ int offl[56];
    int tid = threadIdx.x;
    int zb = blockIdx.z;
    const bf16* inz = in + (long long)zb * PB2E;

    for (int j = tid; j < 448; j += 256) {
        int t = j / 16, ic = j % 16;
        wlds[j] = (t < 27) ? (short)bfbits(w[ic * 27 + t]) : (short)0;
    }
    if (tid < 56) {
        int c = tid / 4, g = tid % 4;
        int t = 2 * c + (g >> 1); if (t > 26) t = 26;   // K-pad: A is zero there
        int off = ((t / 9) * 3 + (t / 3) % 3) * 66 + (t % 3);
        offl[tid] = off * 2 + (g & 1);
    }

    int hw = blockIdx.x;
    int h = hw / 3, w0 = (hw % 3) * 64;
    int dq = blockIdx.y * 4;
    // stage padded planes dq..dq+5, rows h..h+2, px w0..w0+65 (16ch = 2 uint4/px)
    const uint4* src = reinterpret_cast<const uint4*>(inz);
    for (int j = tid; j < 2376; j += 256) {
        int half = j & 1, pxl = j >> 1;
        int p = pxl / 198, rem = pxl % 198;
        int r = rem / 66, c = rem % 66;
        sB[j] = src[(((long long)(dq + p) * 98 + (h + r)) * 194 + (w0 + c)) * 2 + half];
    }
    __syncthreads();

    int wid = tid >> 6, lane = tid & 63;
    int g = lane >> 4, pxi = lane & 15;
    const uint4* sBw = sB + wid * 396;       // wave's plane window (wid..wid+2 via kd)

    int offr[14];
#pragma unroll
    for (int c = 0; c < 14; ++c) offr[c] = offl[c * 4 + g];
    short8v af[14];
    short8v zv = {0,0,0,0,0,0,0,0};
#pragma unroll
    for (int c = 0; c < 14; ++c)
        af[c] = (pxi == 0) ? *reinterpret_cast<const short8v*>(&wlds[32 * c + 8 * g]) : zv;

    f32x4 acc[4];
#pragma unroll
    for (int pg = 0; pg < 4; ++pg) {
        f32x4 a = {0.f, 0.f, 0.f, 0.f};
        int pcol = (pg * 16 + pxi) * 2;
#pragma unroll
        for (int c = 0; c < 14; ++c) {
            short8v bf = *reinterpret_cast<const short8v*>(&sBw[offr[c] + pcol]);
            a = __builtin_amdgcn_mfma_f32_16x16x32_bf16(af[c], bf, a, 0, 0, 0);
        }
        acc[pg] = a;
    }

    // D row 0 lives in lanes 0-15, reg 0 (col = lane)
    float* outz = out + (long long)zb * 884736;
    if (lane < 16) {
        long long base = ((long long)(dq + wid) * 96 + h) * 192 + w0 + lane;
#pragma unroll
        for (int pg = 0; pg < 4; ++pg)
            outz[base + pg * 16] = acc[pg][0];
    }
}

// ====================== REST ======================
__global__ __launch_bounds__(256) void corr2_k(
    const float* __restrict__ fl, const float* __restrict__ fr,
    float* __restrict__ cost)
{
    const int C = 32, D = 48, H = 96, W = 192;
    __shared__ float sfl[64 * 33];
    __shared__ float sfr[111 * 33];

    int w0 = blockIdx.x * 64, h = blockIdx.y, b = blockIdx.z;
    int tid = threadIdx.x;

    for (int j = tid; j < 64 * C; j += 256) {
        int w = j % 64, c = j / 64;
        sfl[w * 33 + c] = fl[(((long long)b * C + c) * H + h) * W + w0 + w];
    }
    for (int j = tid; j < 111 * C; j += 256) {
        int wp = j % 111, c = j / 111;
        int gw = w0 - 47 + wp;
        sfr[wp * 33 + c] = (gw >= 0) ? fr[(((long long)b * C + c) * H + h) * W + gw] : 0.f;
    }
    __syncthreads();

    int w = tid & 63, dg = tid >> 6;
    float flr[32];
#pragma unroll
    for (int c = 0; c < 32; ++c) flr[c] = sfl[w * 33 + c];

    for (int dd = 0; dd < 12; ++dd) {
        int d = dg * 12 + dd;
        int wi = w - d + 47;
        float a = 0.f;
#pragma unroll
        for (int c = 0; c < 32; ++c) a = fmaf(flr[c], sfr[wi * 33 + c], a);
        cost[(((long long)b * D + d) * H + h) * W + w0 + w] = a * (1.0f / 32.0f);
    }
}

__global__ void softdisp_k(const float* __restrict__ c3, float* __restrict__ dl,
                           int B, int H, int W)
{
    const int D = 48;
    long long idx = (long long)blockIdx.x * blockDim.x + threadIdx.x;
    long long total = (long long)B * H * W;
    if (idx >= total) return;
    int b = (int)(idx / ((long long)H * W));
    long long rem = idx % ((long long)H * W);
    const float* p = c3 + ((long long)b * D) * H * W + rem;
    long long st = (long long)H * W;

    float v[48];
    float mn = 1e30f;
#pragma unroll
    for (int d = 0; d < D; ++d) { v[d] = p[d * st]; mn = fminf(mn, v[d]); }
    float se = 0.f, sd = 0.f;
#pragma unroll
    for (int d = 0; d < D; ++d) {
        float e = expf(mn - v[d]);
        se += e;
        sd += e * (float)d;
    }
    dl[idx] = sd / se;
}

// ---- fused refinement with inline bilinear upsample from DL ----
__global__ __launch_bounds__(256) void refine_fused(
    const float* __restrict__ dlow, const float* __restrict__ w1,
    const float* __restrict__ s1, const float* __restrict__ b1,
    const float* __restrict__ w2, float* __restrict__ out)
{
    const int H = 384, W = 768, Hl = 96, Wl = 192;
    __shared__ float sdu[20][21];
    __shared__ float smid[18][18][20];
    __shared__ float w1l[144], s1l[16], b1l[16], w2l[144];
    int tid = threadIdx.x;
    if (tid < 144) {
        w1l[tid] = w1[tid];
        int ic = tid / 9, tap = tid % 9;
        w2l[tap * 16 + ic] = w2[tid];
    } else if (tid < 160) {
        s1l[tid - 144] = s1[tid - 144]; b1l[tid - 144] = b1[tid - 144];
    }

    int b = blockIdx.z, h0 = blockIdx.y * 16, w0 = blockIdx.x * 16;
    const float* dlb = dlow + (long long)b * Hl * Wl;
    for (int j = tid; j < 400; j += 256) {
        int i = j / 20, k = j % 20;
        int y = h0 - 2 + i, x = w0 - 2 + k;
        float v = 0.f;
        if (y >= 0 && y < H && x >= 0 && x < W) {
            float sy = (y + 0.5f) * 0.25f - 0.5f;
            float sx = (x + 0.5f) * 0.25f - 0.5f;
            sy = fminf(fmaxf(sy, 0.f), (float)(Hl - 1));
            sx = fminf(fmaxf(sx, 0.f), (float)(Wl - 1));
            int y0 = (int)sy, x0 = (int)sx;
            int y1 = min(y0 + 1, Hl - 1), x1 = min(x0 + 1, Wl - 1);
            float fy = sy - y0, fx = sx - x0;
            v = 4.0f * ((1.f - fy) * ((1.f - fx) * dlb[y0 * Wl + x0] + fx * dlb[y0 * Wl + x1])
                      +        fy  * ((1.f - fx) * dlb[y1 * Wl + x0] + fx * dlb[y1 * Wl + x1]));
        }
        sdu[i][k] = v;
    }
    __syncthreads();

    for (int idx = tid; idx < 324; idx += 256) {
        int i = idx / 18, j = idx % 18;
        int gy = h0 - 1 + i, gx = w0 - 1 + j;
        bool inimg = (gy >= 0 && gy < H && gx >= 0 && gx < W);
        float t[9];
#pragma unroll
        for (int kh = 0; kh < 3; ++kh)
#pragma unroll
            for (int kw = 0; kw < 3; ++kw) t[kh * 3 + kw] = sdu[i + kh][j + kw];
        float m[16];
#pragma unroll
        for (int oc = 0; oc < 16; ++oc) {
            float s = 0.f;
#pragma unroll
            for (int k = 0; k < 9; ++k) s = fmaf(t[k], w1l[oc * 9 + k], s);
            m[oc] = inimg ? fmaxf(s * s1l[oc] + b1l[oc], 0.f) : 0.f;
        }
#pragma unroll
        for (int q = 0; q < 4; ++q)
            *reinterpret_cast<float4*>(&smid[i][j][q * 4]) =
                make_float4(m[q*4], m[q*4+1], m[q*4+2], m[q*4+3]);
    }
    __syncthreads();

    int i = tid >> 4, j = tid & 15;
    float s = 0.f;
#pragma unroll
    for (int kh = 0; kh < 3; ++kh)
#pragma unroll
        for (int kw = 0; kw < 3; ++kw) {
            const float* mp = &smid[i + kh][j + kw][0];
            const float* wp = &w2l[(kh * 3 + kw) * 16];
#pragma unroll
            for (int q = 0; q < 4; ++q) {
                float4 x = *reinterpret_cast<const float4*>(mp + q * 4);
                s = fmaf(x.x, wp[q*4+0], s);
                s = fmaf(x.y, wp[q*4+1], s);
                s = fmaf(x.z, wp[q*4+2], s);
                s = fmaf(x.w, wp[q*4+3], s);
            }
        }
    out[(long long)b * H * W + (long long)(h0 + i) * W + w0 + j] = fmaxf(s, 0.f);
}

extern "C" void kernel_launch(void* const* d_in, const int* in_sizes, int n_in,
                              void* d_out, int out_size, void* d_ws, size_t ws_size,
                              hipStream_t stream)
{
    const float* img_l = (const float*)d_in[0];
    const float* img_r = (const float*)d_in[1];
    const float* e_w1 = (const float*)d_in[2];
    const float* e_w2 = (const float*)d_in[3];
    const float* e_w3 = (const float*)d_in[4];
    const float* e_w4 = (const float*)d_in[5];
    const float* e_s1 = (const float*)d_in[6];
    const float* e_s2 = (const float*)d_in[7];
    const float* e_s3 = (const float*)d_in[8];
    const float* e_s4 = (const float*)d_in[9];
    const float* e_b1 = (const float*)d_in[10];
    const float* e_b2 = (const float*)d_in[11];
    const float* e_b3 = (const float*)d_in[12];
    const float* e_b4 = (const float*)d_in[13];
    const float* a_w1 = (const float*)d_in[14];
    const float* a_s1 = (const float*)d_in[15];
    const float* a_b1 = (const float*)d_in[16];
    const float* a_w2 = (const float*)d_in[17];
    const float* a_s2 = (const float*)d_in[18];
    const float* a_b2 = (const float*)d_in[19];
    const float* a_w3 = (const float*)d_in[20];
    const float* r_w1 = (const float*)d_in[21];
    const float* r_s1 = (const float*)d_in[22];
    const float* r_b1 = (const float*)d_in[23];
    const float* r_w2 = (const float*)d_in[24];

    const int B = 4, H = 384, W = 768, H4 = 96, W4 = 192, D = 48;
    const long long HW4 = (long long)H4 * W4;
    const long long DHW = (long long)D * HW4;
    const long long E12E = E12_BS / 2;
    const long long P1E = 98LL * 194 * 8;
    const long long P2E = 98LL * 194 * 16;

    float* out_disp = (float*)d_out;
    float* FL       = out_disp + 1179648;

    // ---- workspace layout (peak 166.6 MB) ----
    char* ws = (char*)d_ws;
    bf16*  E1pad = (bf16*)(ws + 0);
    bf16*  E2pad = (bf16*)(ws + 19170304);
    bf16*  E3pad = (bf16*)(ws + 38340608);
    float* FR    = (float*)(ws + 48074752);
    float* COST  = (float*)(ws + 0);
    bf16*  C1pad = (bf16*) (ws + 14155776);     // 2 x PB1E
    bf16*  C2pad = (bf16*) (ws + 44574976);     // 4 x PB2E
    float* C3    = COST;
    float* DL    = (float*)(ws + 166251776);

    dim3 blk(256);

    halo2d_k<<<dim3(10, 1, 16), blk, 0, stream>>>(E1pad, E12E, 1, 0, 194, 386, 2);
    halo2d_k<<<dim3(10, 1, 8),  blk, 0, stream>>>(E3pad, E3_BS / 2, 1, 0, 98, 194, 4);

    conv_e1<<<dim3(72, 1, 8), blk, 0, stream>>>(img_l, img_r, e_w1, e_s1, e_b1, E1pad);
    conv_e2_mfma<<<dim3(288, 1, 8), blk, 0, stream>>>(E1pad, e_w2, e_s2, e_b2, E2pad);
    conv_e3_mfma<<<dim3(72, 2, 8), blk, 0, stream>>>(E2pad, e_w3, e_s3, e_b3, E3pad);
    conv_e4_mfma<<<dim3(72, 2, 8), blk, 0, stream>>>(E3pad, e_w4, e_s4, e_b4, FL, FR);

    corr2_k<<<dim3(3, 96, 4), blk, 0, stream>>>(FL, FR, COST);

    // halo zeroing: C1 (2 buffers), C2 (4 buffers incl. planes 0/49 — now READ by conv3_mfma)
    zero_planes_k<<<dim3(75, 2, 2), blk, 0, stream>>>(C1pad, PB1E, P1E / 8, 49);
    halo2d_k<<<dim3(3, 1, 96), blk, 0, stream>>>(C1pad + P1E, PB1E, 48, P1E, 98, 194, 1);
    zero_planes_k<<<dim3(75, 2, 4), blk, 0, stream>>>(C2pad, PB2E, P2E / 8, 49);
    halo2d_k<<<dim3(5, 1, 192), blk, 0, stream>>>(C2pad + P2E, PB2E, 48, P2E, 98, 194, 2);

    // --- conv1+conv2 per super-batch; conv2 fills C2 buffers sb*2, sb*2+1 ---
    for (int sb = 0; sb < 2; ++sb) {
        conv1_nhwc<<<dim3(18, 48, 2), blk, 0, stream>>>(
            COST + sb * 2 * DHW, a_w1, a_s1, a_b1, C1pad);
        conv2_mfma<<<dim3(288, 12, 2), blk, 0, stream>>>(
            C1pad, a_w2, a_s2, a_b2, C2pad + sb * 2 * PB2E);
    }

    // --- conv3 via MFMA: all 4 batches, one launch ---
    conv3_mfma<<<dim3(288, 12, 4), blk, 0, stream>>>(C2pad, a_w3, C3);

    softdisp_k<<<cdiv(4LL*H4*W4, 256), blk, 0, stream>>>(C3, DL, B, H4, W4);

    refine_fused<<<dim3(48, 24, 4), blk, 0, stream>>>(
        DL, r_w1, r_s1, r_b1, r_w2, out_disp);
}

// Round 23
// 371.637 us; speedup vs baseline: 1.1313x; 1.0611x over previous
//
#include <hip/hip_runtime.h>
#include <hip/hip_bf16.h>

typedef __hip_bfloat16 bf16;
typedef __attribute__((ext_vector_type(8))) short short8v;
typedef __attribute__((ext_vector_type(4))) float f32x4;

static inline int cdiv(long long a, int b){ return (int)((a + b - 1) / b); }

__device__ __forceinline__ float uaf(unsigned u){ return __uint_as_float(u); }
__device__ __forceinline__ float ldf(const bf16* p){ return __bfloat162float(*p); }
__device__ __forceinline__ void stf(bf16* p, float v){ *p = __float2bfloat16(v); }

__device__ __forceinline__ void load4v(const float* p, float& a, float& b, float& c, float& d){
    float4 v = *reinterpret_cast<const float4*>(p); a = v.x; b = v.y; c = v.z; d = v.w;
}
__device__ __forceinline__ unsigned short bfbits(float v){
    bf16 h = __float2bfloat16(v); unsigned short s; __builtin_memcpy(&s, &h, 2); return s;
}

// ====================== HALO ZEROING ======================
__global__ void halo2d_k(bf16* buf, long long bstride, int nsub, long long sstride,
                         int Hp, int Wp, int Cv)
{
    int z = blockIdx.z;
    bf16* b = buf + (long long)(z / nsub) * bstride + (long long)(z % nsub) * sstride;
    uint4 zz = make_uint4(0, 0, 0, 0);
    int rowV = Wp * Cv;
    int totalV = 2 * rowV + (Hp - 2) * 2 * Cv;
    for (int i = blockIdx.x * 256 + threadIdx.x; i < totalV; i += gridDim.x * 256) {
        long long off;
        if (i < rowV) off = i;
        else if (i < 2 * rowV) off = (long long)(Hp - 1) * rowV + (i - rowV);
        else {
            int k = i - 2 * rowV;
            int h = 1 + k / (2 * Cv);
            int r = k % (2 * Cv);
            int wc = (r < Cv) ? 0 : (Wp - 1);
            off = (long long)h * rowV + (long long)wc * Cv + (r < Cv ? r : r - Cv);
        }
        reinterpret_cast<uint4*>(b)[off] = zz;
    }
}

__global__ void zero_planes_k(bf16* buf, long long bstride, long long planeV, int lastPlane)
{
    int b = blockIdx.z, p = blockIdx.y;
    uint4 zz = make_uint4(0, 0, 0, 0);
    bf16* base = buf + (long long)b * bstride;
    long long pl = p ? (long long)lastPlane * planeV : 0;
    for (long long i = blockIdx.x * 256 + threadIdx.x; i < planeV; i += (long long)gridDim.x * 256)
        reinterpret_cast<uint4*>(base)[pl + i] = zz;
}

// ====================== ENCODER (NHWC bf16 chain) ======================
#define E12_BS 2396288LL   // bytes per img, 194*386*16*2
#define E3_BS  1216768LL   // 98*194*32*2

__global__ __launch_bounds__(256) void conv_e1(
    const float* __restrict__ in0, const float* __restrict__ in1,
    const float* __restrict__ w, const float* __restrict__ sc, const float* __restrict__ bi,
    bf16* __restrict__ out)
{
    const int H = 384, W = 768, NW = 96;
    int img = blockIdx.z;
    const float* in = (img >= 4) ? in1 + (long long)(img - 4) * 3 * 294912
                                 : in0 + (long long)img * 3 * 294912;

    __shared__ float wl[432];
    __shared__ float sl[16], bl[16];
    for (int j = threadIdx.x; j < 432; j += 256) {
        int k = j / 16, o = j % 16;
        wl[j] = w[o * 27 + k];
    }
    if (threadIdx.x < 16) { sl[threadIdx.x] = sc[threadIdx.x]; bl[threadIdx.x] = bi[threadIdx.x]; }
    __syncthreads();

    int unit = blockIdx.x * 256 + threadIdx.x;
    int h = unit / NW, wseg = unit % NW, w0 = wseg << 2;
    const long long HW = (long long)H * W;

    float acc[16][4];
#pragma unroll
    for (int o = 0; o < 16; ++o){ acc[o][0]=0.f; acc[o][1]=0.f; acc[o][2]=0.f; acc[o][3]=0.f; }

    for (int ic = 0; ic < 3; ++ic) {
        const float* ip = in + (long long)ic * HW;
#pragma unroll
        for (int kh = 0; kh < 3; ++kh) {
            int ih = 2 * h + kh - 1;
            if (ih < 0 || ih >= H) continue;
            const float* row = ip + (long long)ih * W;
            float x0,x1,x2,x3,x4,x5,x6,x7;
            load4v(row + 2 * w0,     x0, x1, x2, x3);
            load4v(row + 2 * w0 + 4, x4, x5, x6, x7);
            float xm = (w0 > 0) ? row[2 * w0 - 1] : 0.f;
            const float* wk = wl + (ic * 9 + kh * 3) * 16;
#pragma unroll
            for (int o = 0; o < 16; ++o) {
                float wa = wk[o], wb = wk[16 + o], wc = wk[32 + o];
                acc[o][0] = fmaf(xm, wa, fmaf(x0, wb, fmaf(x1, wc, acc[o][0])));
                acc[o][1] = fmaf(x1, wa, fmaf(x2, wb, fmaf(x3, wc, acc[o][1])));
                acc[o][2] = fmaf(x3, wa, fmaf(x4, wb, fmaf(x5, wc, acc[o][2])));
                acc[o][3] = fmaf(x5, wa, fmaf(x6, wb, fmaf(x7, wc, acc[o][3])));
            }
        }
    }
    char* ob = (char*)out + (long long)img * E12_BS;
#pragma unroll
    for (int i = 0; i < 4; ++i) {
        float v[16];
#pragma unroll
        for (int o = 0; o < 16; ++o) v[o] = fmaxf(acc[o][i] * sl[o] + bl[o], 0.f);
        uint4 u0, u1;
        u0.x = (unsigned)bfbits(v[0])  | ((unsigned)bfbits(v[1])  << 16);
        u0.y = (unsigned)bfbits(v[2])  | ((unsigned)bfbits(v[3])  << 16);
        u0.z = (unsigned)bfbits(v[4])  | ((unsigned)bfbits(v[5])  << 16);
        u0.w = (unsigned)bfbits(v[6])  | ((unsigned)bfbits(v[7])  << 16);
        u1.x = (unsigned)bfbits(v[8])  | ((unsigned)bfbits(v[9])  << 16);
        u1.y = (unsigned)bfbits(v[10]) | ((unsigned)bfbits(v[11]) << 16);
        u1.z = (unsigned)bfbits(v[12]) | ((unsigned)bfbits(v[13]) << 16);
        u1.w = (unsigned)bfbits(v[14]) | ((unsigned)bfbits(v[15]) << 16);
        char* p = ob + ((long long)(h + 1) * 386 + (w0 + i + 1)) * 32;
        *reinterpret_cast<uint4*>(p)      = u0;
        *reinterpret_cast<uint4*>(p + 16) = u1;
    }
}

__global__ __launch_bounds__(256) void conv_e2_mfma(
    const bf16* __restrict__ in, const float* __restrict__ w,
    const float* __restrict__ sc, const float* __restrict__ bi,
    bf16* __restrict__ out)
{
    __shared__ short alds[16 * 160];
    __shared__ int offl[20];
    int tid = threadIdx.x;
    for (int j = tid; j < 16 * 160; j += 256) {
        int oc = j / 160, kk = j % 160;
        short v = 0;
        if (kk < 144) { int tap = kk / 16, ic = kk % 16; v = (short)bfbits(w[oc * 144 + ic * 9 + tap]); }
        alds[j] = v;
    }
    if (tid < 20) {
        int c = tid / 4, g = tid % 4;
        int tap = 2 * c + (g >> 1); if (tap > 8) tap = 8;
        offl[tid] = ((tap / 3) * 386 + (tap % 3)) * 32 + (g & 1) * 16;
    }
    __syncthreads();

    int wid = tid >> 6, lane = tid & 63;
    int wt = blockIdx.x * 4 + wid;
    int h = wt / 6, w0 = (wt % 6) * 64;
    int img = blockIdx.z;
    int g = lane >> 4, px = lane & 15;

    const char* bp = (const char*)in + (long long)img * E12_BS
                   + ((long long)h * 386 + (w0 + px)) * 32;
    int offr[5];
#pragma unroll
    for (int c = 0; c < 5; ++c) offr[c] = offl[c * 4 + g];
    short8v af[5];
#pragma unroll
    for (int c = 0; c < 5; ++c)
        af[c] = *reinterpret_cast<const short8v*>(&alds[px * 160 + 32 * c + 8 * g]);

    f32x4 acc[4];
#pragma unroll
    for (int pg = 0; pg < 4; ++pg) {
        f32x4 a = {0.f, 0.f, 0.f, 0.f};
        const char* bpp = bp + pg * 512;
#pragma unroll
        for (int c = 0; c < 5; ++c) {
            short8v bf = *reinterpret_cast<const short8v*>(bpp + offr[c]);
            a = __builtin_amdgcn_mfma_f32_16x16x32_bf16(af[c], bf, a, 0, 0, 0);
        }
        acc[pg] = a;
    }
    char* ob = (char*)out + (long long)img * E12_BS;
#pragma unroll
    for (int pg = 0; pg < 4; ++pg) {
        float v[4];
#pragma unroll
        for (int r = 0; r < 4; ++r) {
            int oc = g * 4 + r;
            v[r] = fmaxf(acc[pg][r] * sc[oc] + bi[oc], 0.f);
        }
        uint2 u;
        u.x = (unsigned)bfbits(v[0]) | ((unsigned)bfbits(v[1]) << 16);
        u.y = (unsigned)bfbits(v[2]) | ((unsigned)bfbits(v[3]) << 16);
        *reinterpret_cast<uint2*>(ob + ((long long)(h + 1) * 386 + (w0 + pg * 16 + px + 1)) * 32 + g * 8) = u;
    }
}

__global__ __launch_bounds__(256) void conv_e3_mfma(
    const bf16* __restrict__ in, const float* __restrict__ w,
    const float* __restrict__ sc, const float* __restrict__ bi,
    bf16* __restrict__ out)
{
    __shared__ short alds[16 * 160];
    __shared__ int offl[20];
    int tid = threadIdx.x;
    int och = blockIdx.y;
    for (int j = tid; j < 16 * 160; j += 256) {
        int oc = j / 160, kk = j % 160;
        short v = 0;
        if (kk < 144) { int tap = kk / 16, ic = kk % 16; v = (short)bfbits(w[(och * 16 + oc) * 144 + ic * 9 + tap]); }
        alds[j] = v;
    }
    if (tid < 20) {
        int c = tid / 4, g = tid % 4;
        int tap = 2 * c + (g >> 1); if (tap > 8) tap = 8;
        offl[tid] = ((tap / 3) * 386 + (tap % 3)) * 32 + (g & 1) * 16;
    }
    __syncthreads();

    int wid = tid >> 6, lane = tid & 63;
    int wt = blockIdx.x * 4 + wid;
    int h = wt / 3, w0 = (wt % 3) * 64;
    int img = blockIdx.z;
    int g = lane >> 4, px = lane & 15;

    const char* bp = (const char*)in + (long long)img * E12_BS
                   + ((long long)(2 * h) * 386 + 2 * (w0 + px)) * 32;
    int offr[5];
#pragma unroll
    for (int c = 0; c < 5; ++c) offr[c] = offl[c * 4 + g];
    short8v af[5];
#pragma unroll
    for (int c = 0; c < 5; ++c)
        af[c] = *reinterpret_cast<const short8v*>(&alds[px * 160 + 32 * c + 8 * g]);

    f32x4 acc[4];
#pragma unroll
    for (int pg = 0; pg < 4; ++pg) {
        f32x4 a = {0.f, 0.f, 0.f, 0.f};
        const char* bpp = bp + pg * 1024;
#pragma unroll
        for (int c = 0; c < 5; ++c) {
            short8v bf = *reinterpret_cast<const short8v*>(bpp + offr[c]);
            a = __builtin_amdgcn_mfma_f32_16x16x32_bf16(af[c], bf, a, 0, 0, 0);
        }
        acc[pg] = a;
    }
    char* ob = (char*)out + (long long)img * E3_BS;
#pragma unroll
    for (int pg = 0; pg < 4; ++pg) {
        float v[4];
#pragma unroll
        for (int r = 0; r < 4; ++r) {
            int oc = och * 16 + g * 4 + r;
            v[r] = fmaxf(acc[pg][r] * sc[oc] + bi[oc], 0.f);
        }
        uint2 u;
        u.x = (unsigned)bfbits(v[0]) | ((unsigned)bfbits(v[1]) << 16);
        u.y = (unsigned)bfbits(v[2]) | ((unsigned)bfbits(v[3]) << 16);
        *reinterpret_cast<uint2*>(ob + ((long long)(h + 1) * 194 + (w0 + pg * 16 + px + 1)) * 64
                                  + och * 32 + g * 8) = u;
    }
}

__global__ __launch_bounds__(256) void conv_e4_mfma(
    const bf16* __restrict__ in, const float* __restrict__ w,
    const float* __restrict__ sc, const float* __restrict__ bi,
    float* __restrict__ fl, float* __restrict__ fr)
{
    __shared__ short alds[16 * 288];
    __shared__ int offl[36];
    int tid = threadIdx.x;
    int och = blockIdx.y;
    for (int j = tid; j < 16 * 288; j += 256) {
        int oc = j / 288, kk = j % 288;
        int tap = kk / 32, ic = kk % 32;
        alds[j] = (short)bfbits(w[(och * 16 + oc) * 288 + ic * 9 + tap]);
    }
    if (tid < 36) {
        int c = tid / 4, g = tid % 4;
        offl[tid] = ((c / 3) * 194 + (c % 3)) * 64 + g * 16;
    }
    __syncthreads();

    int wid = tid >> 6, lane = tid & 63;
    int wt = blockIdx.x * 4 + wid;
    int h = wt / 3, w0 = (wt % 3) * 64;
    int img = blockIdx.z;
    int g = lane >> 4, px = lane & 15;

    const char* bp = (const char*)in + (long long)img * E3_BS
                   + ((long long)h * 194 + (w0 + px)) * 64;
    int offr[9];
#pragma unroll
    for (int c = 0; c < 9; ++c) offr[c] = offl[c * 4 + g];
    short8v af[9];
#pragma unroll
    for (int c = 0; c < 9; ++c)
        af[c] = *reinterpret_cast<const short8v*>(&alds[px * 288 + 32 * c + 8 * g]);

    f32x4 acc[4];
#pragma unroll
    for (int pg = 0; pg < 4; ++pg) {
        f32x4 a = {0.f, 0.f, 0.f, 0.f};
        const char* bpp = bp + pg * 1024;
#pragma unroll
        for (int c = 0; c < 9; ++c) {
            short8v bf = *reinterpret_cast<const short8v*>(bpp + offr[c]);
            a = __builtin_amdgcn_mfma_f32_16x16x32_bf16(af[c], bf, a, 0, 0, 0);
        }
        acc[pg] = a;
    }
    float* dst = (img < 4) ? fl + (long long)img * 32 * 18432
                           : fr + (long long)(img - 4) * 32 * 18432;
#pragma unroll
    for (int pg = 0; pg < 4; ++pg) {
#pragma unroll
        for (int r = 0; r < 4; ++r) {
            int oc = och * 16 + g * 4 + r;
            float v = fmaxf(acc[pg][r] * sc[oc] + bi[oc], 0.f);
            dst[(long long)oc * 18432 + (long long)h * 192 + w0 + pg * 16 + px] = v;
        }
    }
}

// ====================== AGGREGATION ======================
#define PB1E 7604800LL     // C1pad elems per buffer (50*98*194*8)
#define PB2E 15209600LL    // C2pad elems per buffer (50*98*194*16)

__global__ __launch_bounds__(256) void conv1_nhwc(
    const float* __restrict__ in, const float* __restrict__ w,
    const float* __restrict__ sc, const float* __restrict__ bi,
    bf16* __restrict__ out)
{
    const int H = 96, W = 192, D = 48, NW = 48;
    int zb = blockIdx.z;
    const float* inz = in + (long long)zb * 884736;
    bf16* outz = out + (long long)zb * PB1E;
    int d = blockIdx.y;
    __shared__ float wl[216];
    __shared__ float sl[8], bl[8];
    for (int j = threadIdx.x; j < 216; j += 256) wl[j] = w[j];
    if (threadIdx.x < 8) { sl[threadIdx.x] = sc[threadIdx.x]; bl[threadIdx.x] = bi[threadIdx.x]; }
    __syncthreads();

    int unit = blockIdx.x * 256 + threadIdx.x;
    int h = unit / NW, wseg = unit % NW, w0 = wseg << 2;
    if (h >= H) return;

    float acc[8][4];
#pragma unroll
    for (int o = 0; o < 8; ++o){ acc[o][0]=0.f; acc[o][1]=0.f; acc[o][2]=0.f; acc[o][3]=0.f; }

#pragma unroll
    for (int kd = 0; kd < 3; ++kd) {
        int id = d + kd - 1;
        if (id < 0 || id >= D) continue;
        const float* plane = inz + (long long)id * H * W;
#pragma unroll
        for (int kh = 0; kh < 3; ++kh) {
            int ih = h + kh - 1;
            if (ih < 0 || ih >= H) continue;
            const float* row = plane + (long long)ih * W;
            float x0,x1,x2,x3;
            load4v(row + w0, x0, x1, x2, x3);
            float xl = (wseg > 0)      ? row[w0 - 1] : 0.f;
            float xr = (wseg < NW - 1) ? row[w0 + 4] : 0.f;
            int kb = kd * 9 + kh * 3;
#pragma unroll
            for (int o = 0; o < 8; ++o) {
                float wa = wl[o*27 + kb], wb = wl[o*27 + kb + 1], wc = wl[o*27 + kb + 2];
                acc[o][0] = fmaf(xl, wa, fmaf(x0, wb, fmaf(x1, wc, acc[o][0])));
                acc[o][1] = fmaf(x0, wa, fmaf(x1, wb, fmaf(x2, wc, acc[o][1])));
                acc[o][2] = fmaf(x1, wa, fmaf(x2, wb, fmaf(x3, wc, acc[o][2])));
                acc[o][3] = fmaf(x2, wa, fmaf(x3, wb, fmaf(xr, wc, acc[o][3])));
            }
        }
    }
#pragma unroll
    for (int i = 0; i < 4; ++i) {
        uint4 u;
        float v[8];
#pragma unroll
        for (int o = 0; o < 8; ++o) v[o] = fmaxf(acc[o][i] * sl[o] + bl[o], 0.f);
        u.x = (unsigned)bfbits(v[0]) | ((unsigned)bfbits(v[1]) << 16);
        u.y = (unsigned)bfbits(v[2]) | ((unsigned)bfbits(v[3]) << 16);
        u.z = (unsigned)bfbits(v[4]) | ((unsigned)bfbits(v[5]) << 16);
        u.w = (unsigned)bfbits(v[6]) | ((unsigned)bfbits(v[7]) << 16);
        long long idx = (((long long)(d + 1) * 98 + (h + 1)) * 194 + (w0 + 1 + i)) * 8;
        *reinterpret_cast<uint4*>(&outz[idx]) = u;
    }
}

__global__ __launch_bounds__(256) void conv2_mfma(
    const bf16* __restrict__ in, const float* __restrict__ w,
    const float* __restrict__ sc, const float* __restrict__ bi,
    bf16* __restrict__ out)
{
    __shared__ short alds[16 * 224];
    __shared__ uint4 sB[6 * 3 * 66];
    __shared__ int offl[28];
    int tid = threadIdx.x;
    int zb = blockIdx.z;
    const bf16* inz = in + (long long)zb * PB1E;
    for (int j = tid; j < 16 * 224; j += 256) {
        int oc = j / 224, kk = j % 224;
        short v = 0;
        if (kk < 216) { int t = kk / 8, ic = kk % 8; v = (short)bfbits(w[(oc * 8 + ic) * 27 + t]); }
        alds[j] = v;
    }
    if (tid < 28) {
        int t = (tid < 27) ? tid : 26;
        int kd = t / 9, kh = (t / 3) % 3, kw = t % 3;
        offl[tid] = (kd * 3 + kh) * 66 + kw;
    }

    int hw = blockIdx.x;
    int h = hw / 3, w0 = (hw % 3) * 64;
    int dq = blockIdx.y * 4;
    for (int j = tid; j < 1188; j += 256) {
        int p = j / 198, rem = j % 198;
        int r = rem / 66, c = rem % 66;
        sB[j] = *reinterpret_cast<const uint4*>(
            inz + (((long long)(dq + p) * 98 + (h + r)) * 194 + (w0 + c)) * 8);
    }
    __syncthreads();

    int wid = tid >> 6, lane = tid & 63;
    int g = lane >> 4, px = lane & 15;
    int d = dq + wid;

    const uint4* sBw = sB + wid * 198;
    int offr[7];
#pragma unroll
    for (int c = 0; c < 7; ++c) offr[c] = offl[4 * c + g];
    short8v af[7];
#pragma unroll
    for (int c = 0; c < 7; ++c)
        af[c] = *reinterpret_cast<const short8v*>(&alds[px * 224 + 32 * c + 8 * g]);

    f32x4 acc[4];
#pragma unroll
    for (int pg = 0; pg < 4; ++pg) {
        f32x4 a = {0.f, 0.f, 0.f, 0.f};
        int col = pg * 16 + px;
#pragma unroll
        for (int c = 0; c < 7; ++c) {
            short8v bf = *reinterpret_cast<const short8v*>(&sBw[offr[c] + col]);
            a = __builtin_amdgcn_mfma_f32_16x16x32_bf16(af[c], bf, a, 0, 0, 0);
        }
        acc[pg] = a;
    }

    char* ob = (char*)(out + (long long)zb * PB2E);
#pragma unroll
    for (int pg = 0; pg < 4; ++pg) {
        float v[4];
#pragma unroll
        for (int r = 0; r < 4; ++r) {
            int oc = g * 4 + r;
            v[r] = fmaxf(acc[pg][r] * sc[oc] + bi[oc], 0.f);
        }
        long long pxi = ((long long)(d + 1) * 98 + h + 1) * 194 + (w0 + pg * 16 + px + 1);
        uint2 u;
        u.x = (unsigned)bfbits(v[0]) | ((unsigned)bfbits(v[1]) << 16);
        u.y = (unsigned)bfbits(v[2]) | ((unsigned)bfbits(v[3]) << 16);
        *reinterpret_cast<uint2*>(ob + pxi * 32 + g * 8) = u;
    }
}

// ---- conv3 (16->1) via MFMA, 2 output rows/block (round-23: cut row-overlap staging).
// grid (144, 12, 4): bx -> (h0 = (bx/3)*2, w0 = (bx%3)*64), dq = by*4, batch z.
__global__ __launch_bounds__(256) void conv3_mfma(
    const bf16* __restrict__ in, const float* __restrict__ w,
    float* __restrict__ out)
{
    __shared__ uint4 sB[6 * 4 * 66 * 2];     // 6 planes x 4 rows x 66 px x 16ch (50688 B)
    __shared__ short wlds[448] __attribute__((aligned(16)));
    __shared__ int offl[56];
    int tid = threadIdx.x;
    int zb = blockIdx.z;
    const bf16* inz = in + (long long)zb * PB2E;

    for (int j = tid; j < 448; j += 256) {
        int t = j / 16, ic = j % 16;
        wlds[j] = (t < 27) ? (short)bfbits(w[ic * 27 + t]) : (short)0;
    }
    if (tid < 56) {
        int c = tid / 4, g = tid % 4;
        int t = 2 * c + (g >> 1); if (t > 26) t = 26;   // K-pad: A is zero there
        int off = ((t / 9) * 4 + (t / 3) % 3) * 66 + (t % 3);   // plane stride 4 rows
        offl[tid] = off * 2 + (g & 1);
    }

    int hw = blockIdx.x;
    int h0 = (hw / 3) * 2, w0 = (hw % 3) * 64;
    int dq = blockIdx.y * 4;
    // stage padded planes dq..dq+5, rows h0..h0+3, px w0..w0+65 (16ch = 2 uint4/px)
    const uint4* src = reinterpret_cast<const uint4*>(inz);
    for (int j = tid; j < 3168; j += 256) {
        int half = j & 1, pxl = j >> 1;
        int p = pxl / 264, rem = pxl % 264;
        int r = rem / 66, c = rem % 66;
        sB[j] = src[(((long long)(dq + p) * 98 + (h0 + r)) * 194 + (w0 + c)) * 2 + half];
    }
    __syncthreads();

    int wid = tid >> 6, lane = tid & 63;
    int g = lane >> 4, pxi = lane & 15;
    const uint4* sBw = sB + wid * 528;       // wave's plane window (wid..wid+2 via kd)

    int offr[14];
#pragma unroll
    for (int c = 0; c < 14; ++c) offr[c] = offl[c * 4 + g];
    short8v af[14];
    short8v zv = {0,0,0,0,0,0,0,0};
#pragma unroll
    for (int c = 0; c < 14; ++c)
        af[c] = (pxi == 0) ? *reinterpret_cast<const short8v*>(&wlds[32 * c + 8 * g]) : zv;

    f32x4 acc[2][4];
#pragma unroll
    for (int rr = 0; rr < 2; ++rr) {
#pragma unroll
        for (int pg = 0; pg < 4; ++pg) {
            f32x4 a = {0.f, 0.f, 0.f, 0.f};
            int pcol = (pg * 16 + pxi) * 2 + rr * 132;   // row stride = 66 px * 2 uint4
#pragma unroll
            for (int c = 0; c < 14; ++c) {
                short8v bf = *reinterpret_cast<const short8v*>(&sBw[offr[c] + pcol]);
                a = __builtin_amdgcn_mfma_f32_16x16x32_bf16(af[c], bf, a, 0, 0, 0);
            }
            acc[rr][pg] = a;
        }
    }

    // D row 0 lives in lanes 0-15, reg 0 (col = lane)
    float* outz = out + (long long)zb * 884736;
    if (lane < 16) {
#pragma unroll
        for (int rr = 0; rr < 2; ++rr) {
            long long base = ((long long)(dq + wid) * 96 + h0 + rr) * 192 + w0 + lane;
#pragma unroll
            for (int pg = 0; pg < 4; ++pg)
                outz[base + pg * 16] = acc[rr][pg][0];
        }
    }
}

// ====================== REST ======================
__global__ __launch_bounds__(256) void corr2_k(
    const float* __restrict__ fl, const float* __restrict__ fr,
    float* __restrict__ cost)
{
    const int C = 32, D = 48, H = 96, W = 192;
    __shared__ float sfl[64 * 33];
    __shared__ float sfr[111 * 33];

    int w0 = blockIdx.x * 64, h = blockIdx.y, b = blockIdx.z;
    int tid = threadIdx.x;

    for (int j = tid; j < 64 * C; j += 256) {
        int w = j % 64, c = j / 64;
        sfl[w * 33 + c] = fl[(((long long)b * C + c) * H + h) * W + w0 + w];
    }
    for (int j = tid; j < 111 * C; j += 256) {
        int wp = j % 111, c = j / 111;
        int gw = w0 - 47 + wp;
        sfr[wp * 33 + c] = (gw >= 0) ? fr[(((long long)b * C + c) * H + h) * W + gw] : 0.f;
    }
    __syncthreads();

    int w = tid & 63, dg = tid >> 6;
    float flr[32];
#pragma unroll
    for (int c = 0; c < 32; ++c) flr[c] = sfl[w * 33 + c];

    for (int dd = 0; dd < 12; ++dd) {
        int d = dg * 12 + dd;
        int wi = w - d + 47;
        float a = 0.f;
#pragma unroll
        for (int c = 0; c < 32; ++c) a = fmaf(flr[c], sfr[wi * 33 + c], a);
        cost[(((long long)b * D + d) * H + h) * W + w0 + w] = a * (1.0f / 32.0f);
    }
}

__global__ void softdisp_k(const float* __restrict__ c3, float* __restrict__ dl,
                           int B, int H, int W)
{
    const int D = 48;
    long long idx = (long long)blockIdx.x * blockDim.x + threadIdx.x;
    long long total = (long long)B * H * W;
    if (idx >= total) return;
    int b = (int)(idx / ((long long)H * W));
    long long rem = idx % ((long long)H * W);
    const float* p = c3 + ((long long)b * D) * H * W + rem;
    long long st = (long long)H * W;

    float v[48];
    float mn = 1e30f;
#pragma unroll
    for (int d = 0; d < D; ++d) { v[d] = p[d * st]; mn = fminf(mn, v[d]); }
    float se = 0.f, sd = 0.f;
#pragma unroll
    for (int d = 0; d < D; ++d) {
        float e = expf(mn - v[d]);
        se += e;
        sd += e * (float)d;
    }
    dl[idx] = sd / se;
}

// ---- fused refinement with inline bilinear upsample from DL ----
__global__ __launch_bounds__(256) void refine_fused(
    const float* __restrict__ dlow, const float* __restrict__ w1,
    const float* __restrict__ s1, const float* __restrict__ b1,
    const float* __restrict__ w2, float* __restrict__ out)
{
    const int H = 384, W = 768, Hl = 96, Wl = 192;
    __shared__ float sdu[20][21];
    __shared__ float smid[18][18][20];
    __shared__ float w1l[144], s1l[16], b1l[16], w2l[144];
    int tid = threadIdx.x;
    if (tid < 144) {
        w1l[tid] = w1[tid];
        int ic = tid / 9, tap = tid % 9;
        w2l[tap * 16 + ic] = w2[tid];
    } else if (tid < 160) {
        s1l[tid - 144] = s1[tid - 144]; b1l[tid - 144] = b1[tid - 144];
    }

    int b = blockIdx.z, h0 = blockIdx.y * 16, w0 = blockIdx.x * 16;
    const float* dlb = dlow + (long long)b * Hl * Wl;
    for (int j = tid; j < 400; j += 256) {
        int i = j / 20, k = j % 20;
        int y = h0 - 2 + i, x = w0 - 2 + k;
        float v = 0.f;
        if (y >= 0 && y < H && x >= 0 && x < W) {
            float sy = (y + 0.5f) * 0.25f - 0.5f;
            float sx = (x + 0.5f) * 0.25f - 0.5f;
            sy = fminf(fmaxf(sy, 0.f), (float)(Hl - 1));
            sx = fminf(fmaxf(sx, 0.f), (float)(Wl - 1));
            int y0 = (int)sy, x0 = (int)sx;
            int y1 = min(y0 + 1, Hl - 1), x1 = min(x0 + 1, Wl - 1);
            float fy = sy - y0, fx = sx - x0;
            v = 4.0f * ((1.f - fy) * ((1.f - fx) * dlb[y0 * Wl + x0] + fx * dlb[y0 * Wl + x1])
                      +        fy  * ((1.f - fx) * dlb[y1 * Wl + x0] + fx * dlb[y1 * Wl + x1]));
        }
        sdu[i][k] = v;
    }
    __syncthreads();

    for (int idx = tid; idx < 324; idx += 256) {
        int i = idx / 18, j = idx % 18;
        int gy = h0 - 1 + i, gx = w0 - 1 + j;
        bool inimg = (gy >= 0 && gy < H && gx >= 0 && gx < W);
        float t[9];
#pragma unroll
        for (int kh = 0; kh < 3; ++kh)
#pragma unroll
            for (int kw = 0; kw < 3; ++kw) t[kh * 3 + kw] = sdu[i + kh][j + kw];
        float m[16];
#pragma unroll
        for (int oc = 0; oc < 16; ++oc) {
            float s = 0.f;
#pragma unroll
            for (int k = 0; k < 9; ++k) s = fmaf(t[k], w1l[oc * 9 + k], s);
            m[oc] = inimg ? fmaxf(s * s1l[oc] + b1l[oc], 0.f) : 0.f;
        }
#pragma unroll
        for (int q = 0; q < 4; ++q)
            *reinterpret_cast<float4*>(&smid[i][j][q * 4]) =
                make_float4(m[q*4], m[q*4+1], m[q*4+2], m[q*4+3]);
    }
    __syncthreads();

    int i = tid >> 4, j = tid & 15;
    float s = 0.f;
#pragma unroll
    for (int kh = 0; kh < 3; ++kh)
#pragma unroll
        for (int kw = 0; kw < 3; ++kw) {
            const float* mp = &smid[i + kh][j + kw][0];
            const float* wp = &w2l[(kh * 3 + kw) * 16];
#pragma unroll
            for (int q = 0; q < 4; ++q) {
                float4 x = *reinterpret_cast<const float4*>(mp + q * 4);
                s = fmaf(x.x, wp[q*4+0], s);
                s = fmaf(x.y, wp[q*4+1], s);
                s = fmaf(x.z, wp[q*4+2], s);
                s = fmaf(x.w, wp[q*4+3], s);
            }
        }
    out[(long long)b * H * W + (long long)(h0 + i) * W + w0 + j] = fmaxf(s, 0.f);
}

extern "C" void kernel_launch(void* const* d_in, const int* in_sizes, int n_in,
                              void* d_out, int out_size, void* d_ws, size_t ws_size,
                              hipStream_t stream)
{
    const float* img_l = (const float*)d_in[0];
    const float* img_r = (const float*)d_in[1];
    const float* e_w1 = (const float*)d_in[2];
    const float* e_w2 = (const float*)d_in[3];
    const float* e_w3 = (const float*)d_in[4];
    const float* e_w4 = (const float*)d_in[5];
    const float* e_s1 = (const float*)d_in[6];
    const float* e_s2 = (const float*)d_in[7];
    const float* e_s3 = (const float*)d_in[8];
    const float* e_s4 = (const float*)d_in[9];
    const float* e_b1 = (const float*)d_in[10];
    const float* e_b2 = (const float*)d_in[11];
    const float* e_b3 = (const float*)d_in[12];
    const float* e_b4 = (const float*)d_in[13];
    const float* a_w1 = (const float*)d_in[14];
    const float* a_s1 = (const float*)d_in[15];
    const float* a_b1 = (const float*)d_in[16];
    const float* a_w2 = (const float*)d_in[17];
    const float* a_s2 = (const float*)d_in[18];
    const float* a_b2 = (const float*)d_in[19];
    const float* a_w3 = (const float*)d_in[20];
    const float* r_w1 = (const float*)d_in[21];
    const float* r_s1 = (const float*)d_in[22];
    const float* r_b1 = (const float*)d_in[23];
    const float* r_w2 = (const float*)d_in[24];

    const int B = 4, H = 384, W = 768, H4 = 96, W4 = 192, D = 48;
    const long long HW4 = (long long)H4 * W4;
    const long long DHW = (long long)D * HW4;
    const long long E12E = E12_BS / 2;
    const long long P1E = 98LL * 194 * 8;
    const long long P2E = 98LL * 194 * 16;

    float* out_disp = (float*)d_out;
    float* FL       = out_disp + 1179648;

    // ---- workspace layout (peak 166.6 MB) ----
    char* ws = (char*)d_ws;
    bf16*  E1pad = (bf16*)(ws + 0);
    bf16*  E2pad = (bf16*)(ws + 19170304);
    bf16*  E3pad = (bf16*)(ws + 38340608);
    float* FR    = (float*)(ws + 48074752);
    float* COST  = (float*)(ws + 0);
    bf16*  C1pad = (bf16*) (ws + 14155776);     // 2 x PB1E
    bf16*  C2pad = (bf16*) (ws + 44574976);     // 4 x PB2E
    float* C3    = COST;
    float* DL    = (float*)(ws + 166251776);

    dim3 blk(256);

    halo2d_k<<<dim3(10, 1, 16), blk, 0, stream>>>(E1pad, E12E, 1, 0, 194, 386, 2);
    halo2d_k<<<dim3(10, 1, 8),  blk, 0, stream>>>(E3pad, E3_BS / 2, 1, 0, 98, 194, 4);

    conv_e1<<<dim3(72, 1, 8), blk, 0, stream>>>(img_l, img_r, e_w1, e_s1, e_b1, E1pad);
    conv_e2_mfma<<<dim3(288, 1, 8), blk, 0, stream>>>(E1pad, e_w2, e_s2, e_b2, E2pad);
    conv_e3_mfma<<<dim3(72, 2, 8), blk, 0, stream>>>(E2pad, e_w3, e_s3, e_b3, E3pad);
    conv_e4_mfma<<<dim3(72, 2, 8), blk, 0, stream>>>(E3pad, e_w4, e_s4, e_b4, FL, FR);

    corr2_k<<<dim3(3, 96, 4), blk, 0, stream>>>(FL, FR, COST);

    // halo zeroing: C1 (2 buffers), C2 (4 buffers incl. planes 0/49 — read by conv3_mfma)
    zero_planes_k<<<dim3(75, 2, 2), blk, 0, stream>>>(C1pad, PB1E, P1E / 8, 49);
    halo2d_k<<<dim3(3, 1, 96), blk, 0, stream>>>(C1pad + P1E, PB1E, 48, P1E, 98, 194, 1);
    zero_planes_k<<<dim3(75, 2, 4), blk, 0, stream>>>(C2pad, PB2E, P2E / 8, 49);
    halo2d_k<<<dim3(5, 1, 192), blk, 0, stream>>>(C2pad + P2E, PB2E, 48, P2E, 98, 194, 2);

    // --- conv1+conv2 per super-batch; conv2 fills C2 buffers sb*2, sb*2+1 ---
    for (int sb = 0; sb < 2; ++sb) {
        conv1_nhwc<<<dim3(18, 48, 2), blk, 0, stream>>>(
            COST + sb * 2 * DHW, a_w1, a_s1, a_b1, C1pad);
        conv2_mfma<<<dim3(288, 12, 2), blk, 0, stream>>>(
            C1pad, a_w2, a_s2, a_b2, C2pad + sb * 2 * PB2E);
    }

    // --- conv3 via MFMA: all 4 batches, one launch, 2 rows/block ---
    conv3_mfma<<<dim3(144, 12, 4), blk, 0, stream>>>(C2pad, a_w3, C3);

    softdisp_k<<<cdiv(4LL*H4*W4, 256), blk, 0, stream>>>(C3, DL, B, H4, W4);

    refine_fused<<<dim3(48, 24, 4), blk, 0, stream>>>(
        DL, r_w1, r_s1, r_b1, r_w2, out_disp);
}